// Round 2
// baseline (3038.884 us; speedup 1.0000x reference)
//
#include <hip/hip_runtime.h>
#include <math.h>

// RecurrentSlotEncoder: B=16,K=16,N=1024,D=256,L=8
// Algebra: scores = (slots@Wqk) @ h^T      (no K-projection of h)
//          gi     = (attn@h)·rden @ WgiT + bgi, Wgi = W_ih@Wv  (no V-projection)
// R5 structure: ONE persistent kernel for all 16 steps. 256 wgs x 1024 thr,
// ~126KB LDS/wg -> 1 wg/CU -> all co-resident; hand-rolled device-scope grid
// barrier (monotone generation counter + __threadfence). wg=(b, j16): persists
// 16-row K-slice of GRU weights in LDS for the WHOLE kernel. 4 grid barriers
// per step: attn -> GRU+s2 -> FFN -> LN+Qk. Dispatches 53 -> 6.

#define Bn 16
#define KK 16
#define Nn 1024
#define Dn 256
#define Ln 8
#define NWG 256u

// workspace float offsets
#define OFF_WQK   0          // 256*256   Wqk[d][e]
#define OFF_BQK   65536      // 256
#define OFF_WGIT  65792      // 256*768   WgiT[e][jj] = sum_c Wih[jj][c]*Wv[c][e]
#define OFF_BGI   262400     // 768
#define OFF_W2T   263168     // 256*256
#define OFF_WGIR  328704     // 16*256*48 Wgi_r[j][e][g*16+cl]
#define OFF_WHHR  525312     // 16*256*48 Whh_r[j][e][g*16+cl]
#define OFF_SLOTS 721920     // 128*256
#define OFF_QK    754688     // 128*256
#define OFF_PAV   787456     // [b][j][l][d] 16*16*8*256
#define OFF_PDEN  1311744    // [b][j][l]   16*16*8
#define OFF_S2G   1313792    // [b][l][d]   16*8*256
#define OFF_PX    1346560    // [b][j][l][d] 16*16*8*256
#define OFF_BAR   1870848    // 2 uints

__device__ __forceinline__ float sigmoidf_(float x) { return 1.f / (1.f + __expf(-x)); }

// P1: Wqk[d][e] = sum_a Wq[a][d]*Wk[a][e]; bqk[e] = sum_a bq[a]*Wk[a][e]
__global__ __launch_bounds__(256) void p1_kernel(
    const float* __restrict__ Wq, const float* __restrict__ bq,
    const float* __restrict__ Wk, float* __restrict__ Wqk, float* __restrict__ bqk) {
  int w = blockIdx.x, tid = threadIdx.x;
  if (w < 256) {
    float acc = 0.f;
    for (int a = 0; a < 256; ++a) acc += Wq[a * 256 + w] * Wk[a * 256 + tid];
    Wqk[w * 256 + tid] = acc;
  } else {
    float acc = 0.f;
    for (int a = 0; a < 256; ++a) acc += bq[a] * Wk[a * 256 + tid];
    bqk[tid] = acc;
  }
}

// P2: WgiT[e*768+jj] = sum_c Wih[jj][c]*Wv[c][e]; bgi[jj]=bih[jj]+sum_c Wih[jj][c]*bv[c]
__global__ __launch_bounds__(256) void p2_kernel(
    const float* __restrict__ Wih, const float* __restrict__ bih,
    const float* __restrict__ Wv, const float* __restrict__ bv,
    float* __restrict__ WgiT, float* __restrict__ bgi) {
  int d = blockIdx.x, tid = threadIdx.x;
  float a0 = 0.f, a1 = 0.f, a2 = 0.f;
  for (int c = 0; c < 256; ++c) {
    float wv = Wv[c * 256 + d];  // wave-uniform
    a0 += Wih[tid * 256 + c] * wv;
    a1 += Wih[(tid + 256) * 256 + c] * wv;
    a2 += Wih[(tid + 512) * 256 + c] * wv;
  }
  WgiT[d * 768 + tid] = a0;
  WgiT[d * 768 + 256 + tid] = a1;
  WgiT[d * 768 + 512 + tid] = a2;
  if (d < 3) {
    int jj = d * 256 + tid;
    float s = bih[jj];
    for (int c = 0; c < 256; ++c) s += Wih[jj * 256 + c] * bv[c];
    bgi[jj] = s;
  }
}

// P2b: rearranged weight slices for the persistent kernel + W2 transpose.
// wg<16:  Wgi_r[j][e][col48] = WgiT[e][ (col>>4)*256 + 16j + (col&15) ]
// wg<32:  Whh_r[j][e][col48] = Whh[ (col>>4)*256 + 16j + (col&15) ][e]  (LDS transpose)
// else:   W2T 32x32 tile transpose (64 wgs)
__global__ __launch_bounds__(256) void p2b_kernel(
    const float* __restrict__ WgiT, const float* __restrict__ Whh,
    const float* __restrict__ W2,
    float* __restrict__ Wgi_r, float* __restrict__ Whh_r, float* __restrict__ W2T) {
  __shared__ float tile[48 * 257];
  int wg = blockIdx.x, tid = threadIdx.x;
  if (wg < 16) {
    int j = wg, col = tid & 63, e0 = tid >> 6;
    if (col < 48) {
      int g = col >> 4, cl = col & 15;
      for (int eb = 0; eb < 64; ++eb) {
        int e = eb * 4 + e0;
        Wgi_r[j * 12288 + e * 48 + col] = WgiT[e * 768 + g * 256 + 16 * j + cl];
      }
    }
  } else if (wg < 32) {
    int j = wg - 16;
    for (int r = 0; r < 48; ++r) {
      int grow = (r >> 4) * 256 + 16 * j + (r & 15);
      tile[r * 257 + tid] = Whh[grow * 256 + tid];
    }
    __syncthreads();
    int rr = tid & 63, e0 = tid >> 6;
    if (rr < 48) {
      for (int eb = 0; eb < 64; ++eb) {
        int e = eb * 4 + e0;
        Whh_r[j * 12288 + e * 48 + rr] = tile[rr * 257 + e];
      }
    }
  } else {
    int w2 = wg - 32, tr = w2 >> 3, tc = w2 & 7;
    int r = tid >> 5, c = tid & 31;
#pragma unroll
    for (int k = 0; k < 4; ++k)
      tile[(r + 8 * k) * 33 + c] = W2[(tr * 32 + r + 8 * k) * 256 + tc * 32 + c];
    __syncthreads();
#pragma unroll
    for (int k = 0; k < 4; ++k)
      W2T[(tc * 32 + r + 8 * k) * 256 + tr * 32 + c] = tile[c * 33 + (r + 8 * k)];
  }
}

__global__ __launch_bounds__(256) void init_slots_kernel(
    const float* __restrict__ eps, const float* __restrict__ mu,
    const float* __restrict__ lsig, float* __restrict__ slots,
    unsigned* __restrict__ bar) {
  int idx = blockIdx.x * 256 + threadIdx.x;  // 32768
  if (idx < 2) bar[idx] = 0u;
  int r = idx & 2047;
  slots[idx] = mu[r] + expf(lsig[r]) * eps[idx];
}

// Qk = slots @ Wqk + bqk (t=0 only)
__global__ __launch_bounds__(256) void qk0_kernel(
    const float* __restrict__ Wqk, const float* __restrict__ bqk,
    const float* __restrict__ slots, float* __restrict__ Qkout) {
  __shared__ float sl_s[2048];
  int j = blockIdx.x & 7, b = blockIdx.x >> 3, tid = threadIdx.x;
  for (int k = 0; k < 8; ++k) sl_s[tid + k * 256] = slots[b * 2048 + tid + k * 256];
  __syncthreads();
  int l = tid >> 5, ee = j * 32 + (tid & 31);
  float acc = bqk[ee];
  for (int d = 0; d < 256; ++d) acc += sl_s[l * 256 + d] * Wqk[d * 256 + ee];
  Qkout[b * 2048 + l * 256 + ee] = acc;
}

// Device-wide barrier: monotone generation counter. All 256 wgs co-resident
// (1 wg/CU forced by ~126KB LDS). __threadfence() emits the agent-scope L2
// wb/inv needed for cross-XCD visibility.
__device__ __forceinline__ void grid_sync(unsigned* cnt, unsigned* gen, unsigned round) {
  __syncthreads();
  if (threadIdx.x == 0) {
    __threadfence();  // release
    unsigned prev = __hip_atomic_fetch_add(cnt, 1u, __ATOMIC_RELAXED, __HIP_MEMORY_SCOPE_AGENT);
    if (prev == round * NWG - 1u) {
      __hip_atomic_store(gen, round, __ATOMIC_RELAXED, __HIP_MEMORY_SCOPE_AGENT);
    } else {
      unsigned g;
      do {
        __builtin_amdgcn_s_sleep(2);
        g = __hip_atomic_load(gen, __ATOMIC_RELAXED, __HIP_MEMORY_SCOPE_AGENT);
      } while (g < round);
    }
    __threadfence();  // acquire
  }
  __syncthreads();
}

// Persistent fused kernel. wg = (b, j): b via XCD-swizzle so a batch's 16 wgs
// share an XCD. Per step: P1 attn (64 H-rows, 16-row LDS subtiles) -> bar ->
// P2 upd-combine + full-K GRU into column-slice + s2 -> bar -> P45 FFN1 slice
// cols + FFN2 partial -> bar -> P6 (j<8) LN + s3 + next Qk -> bar.
__global__ __launch_bounds__(1024, 4) void fused_kernel(
    const float* __restrict__ H,
    const float* __restrict__ Wgi_r, const float* __restrict__ bgi,
    const float* __restrict__ Whh_r, const float* __restrict__ bhh,
    const float* __restrict__ W1, const float* __restrict__ b1,
    const float* __restrict__ W2T, const float* __restrict__ b2,
    const float* __restrict__ Wqk, const float* __restrict__ bqk,
    const float* __restrict__ ln_g, const float* __restrict__ ln_b,
    float* __restrict__ slots, float* __restrict__ QkG,
    float* __restrict__ S, float* __restrict__ Beta,
    float* __restrict__ pav, float* __restrict__ pden,
    float* __restrict__ s2g, float* __restrict__ px,
    unsigned* __restrict__ bar) {
  __shared__ float smem[32256];  // 129024 B
  float* wgic = smem;            // [256][48]
  float* whhc = smem + 12288;    // [256][48]
  float* scratch = smem + 24576; // 7680 floats, phase-local overlays

  int wid = blockIdx.x;
  int xcd = wid & 7, slot = wid >> 3;
  int b = xcd * 2 + (slot >> 4), j = slot & 15;
  int tid = threadIdx.x;

  // one-time: persist GRU weight slices
  {
    const float4* gsrc = (const float4*)(Wgi_r + j * 12288);
    const float4* hsrc = (const float4*)(Whh_r + j * 12288);
    float4* gdst = (float4*)wgic;
    float4* hdst = (float4*)whhc;
    for (int i = tid; i < 3072; i += 1024) { gdst[i] = gsrc[i]; hdst[i] = hsrc[i]; }
  }
  unsigned* cnt = bar;
  unsigned* gen = bar + 1;
  unsigned rnd = 0;
  __syncthreads();

  for (int t = 0; t < KK; ++t) {
    // ================= P1: attention partials =================
    {
      float* hs = scratch;           // [16][260] = 4160
      float* es = scratch + 4160;    // [64][8]   = 512
      float* avred = scratch + 4672; // [8][256]  = 2048
      float acc8[8];
#pragma unroll
      for (int i = 0; i < 8; ++i) acc8[i] = 0.f;
      const float* Hb = H + (((long)(b * 16) + t) * 1024 + j * 64) * 256;
      const float* Qkb = QkG + b * 2048;
      for (int st = 0; st < 4; ++st) {
        __syncthreads();
        {  // stage 16 rows
          const float4* src = (const float4*)(Hb + st * 4096);
          int r = tid >> 6, d4 = tid & 63;
          float4 v = src[tid];
          float* dst = &hs[r * 260 + d4 * 4];
          ((float2*)dst)[0] = make_float2(v.x, v.y);
          ((float2*)dst)[1] = make_float2(v.z, v.w);
        }
        __syncthreads();
        {  // phase A: wave wv handles row st*16+wv; lane=(l, e8)
          int wv = tid >> 6, lane = tid & 63, l = lane >> 3, e8 = lane & 7;
          const float4* hr = (const float4*)(&hs[wv * 260 + e8 * 32]);
          const float4* qr = (const float4*)(Qkb + l * 256 + e8 * 32);
          float a = 0.f;
#pragma unroll
          for (int i = 0; i < 8; ++i) {
            float4 hv = hr[i], qv = qr[i];
            a += hv.x * qv.x + hv.y * qv.y + hv.z * qv.z + hv.w * qv.w;
          }
          a += __shfl_xor(a, 1); a += __shfl_xor(a, 2); a += __shfl_xor(a, 4);
          if (e8 == 0) es[(st * 16 + wv) * 8 + l] = __expf(a * 0.0625f);
        }
        __syncthreads();
        {  // phase B: (g, d) accumulates 4 rows
          int g = tid >> 8, d = tid & 255;
#pragma unroll
          for (int rr = 0; rr < 4; ++rr) {
            int r = g * 4 + rr;
            float hv = hs[r * 260 + d];
            const float4* ep = (const float4*)(&es[(st * 16 + r) * 8]);
            float4 e0 = ep[0], e1 = ep[1];
            acc8[0] += e0.x * hv; acc8[1] += e0.y * hv;
            acc8[2] += e0.z * hv; acc8[3] += e0.w * hv;
            acc8[4] += e1.x * hv; acc8[5] += e1.y * hv;
            acc8[6] += e1.z * hv; acc8[7] += e1.w * hv;
          }
        }
      }
      __syncthreads();
      if (tid < 512) {  // Beta (unnormalized) bulk write
        int l = tid >> 6, r = tid & 63;
        Beta[(((long)(b * 16) + t) * 8 + l) * 1024 + j * 64 + r] = es[r * 8 + l];
      }
      if (tid < 64) {  // den partial
        int l = tid >> 3, ch = tid & 7;
        float s = 0.f;
#pragma unroll
        for (int i = 0; i < 8; ++i) s += es[(ch * 8 + i) * 8 + l];
        s += __shfl_xor(s, 1); s += __shfl_xor(s, 2); s += __shfl_xor(s, 4);
        if (ch == 0) pden[(b * 16 + j) * 8 + l] = s;
      }
      // av accumulate over g-groups (sequential)
      for (int g2 = 0; g2 < 4; ++g2) {
        if ((tid >> 8) == g2) {
          int d = tid & 255;
#pragma unroll
          for (int l = 0; l < 8; ++l) {
            if (g2 == 0) avred[l * 256 + d] = acc8[l];
            else avred[l * 256 + d] += acc8[l];
          }
        }
        __syncthreads();
      }
      for (int s = tid; s < 2048; s += 1024)
        pav[(long)(b * 16 + j) * 2048 + s] = avred[s];
    }
    grid_sync(cnt, gen, ++rnd);

    // ================= P2: upd combine + GRU + s2 slice =================
    {
      float* upd = scratch;          // 2048
      float* sls = scratch + 2048;   // 2048
      float* gsum = scratch + 4096;  // 768
      float* dens = scratch + 4864;  // 8
      if (tid < 8) {
        float s = 0.f;
        for (int jj = 0; jj < 16; ++jj) s += pden[(b * 16 + jj) * 8 + tid];
        dens[tid] = 1.f / s;
      }
      sls[tid] = slots[b * 2048 + tid];
      sls[tid + 1024] = slots[b * 2048 + tid + 1024];
      __syncthreads();
      for (int s = tid; s < 2048; s += 1024) {
        int l = s >> 8;
        float a = 0.f;
#pragma unroll
        for (int jj = 0; jj < 16; ++jj) a += pav[(long)(b * 16 + jj) * 2048 + s];
        upd[s] = a * dens[l];
      }
      if (tid < 512) {  // Beta normalize (own 64 rows)
        int l = tid >> 6, r = tid & 63;
        long o = (((long)(b * 16) + t) * 8 + l) * 1024 + j * 64 + r;
        Beta[o] *= dens[l];
      }
      __syncthreads();
      // gi/gh: 384 threads, (gh6, l2, cl); each thread 2 slot-rows
      if (tid < 384) {
        int gh6 = tid >> 6, l2 = (tid >> 4) & 3, cl = tid & 15;
        bool isg = gh6 < 3;
        int g = isg ? gh6 : gh6 - 3;
        const float* wb = (isg ? wgic : whhc) + g * 16 + cl;
        const float* x0 = (isg ? upd : sls) + l2 * 256;
        const float* x1 = x0 + 1024;  // (l2+4)*256
        float a0 = 0.f, a1 = 0.f;
#pragma unroll 8
        for (int e = 0; e < 256; ++e) {
          float w = wb[e * 48];
          a0 += x0[e] * w;
          a1 += x1[e] * w;
        }
        float bias = isg ? bgi[g * 256 + 16 * j + cl] : bhh[g * 256 + 16 * j + cl];
        gsum[gh6 * 128 + l2 * 16 + cl] = a0 + bias;
        gsum[gh6 * 128 + (l2 + 4) * 16 + cl] = a1 + bias;
      }
      __syncthreads();
      if (tid < 128) {
        int l = tid >> 4, cl = tid & 15;
        float r = sigmoidf_(gsum[tid] + gsum[384 + tid]);
        float z = sigmoidf_(gsum[128 + tid] + gsum[512 + tid]);
        float n = tanhf(gsum[256 + tid] + r * gsum[640 + tid]);
        float s2 = (1.f - z) * n + z * sls[l * 256 + 16 * j + cl];
        s2g[b * 2048 + l * 256 + 16 * j + cl] = s2;
      }
    }
    grid_sync(cnt, gen, ++rnd);

    // ================= P45: FFN =================
    {
      float* wbuf = scratch;         // w1c [256*17] then w2r [16*256]
      float* s2f = scratch + 4352;   // 2048
      float* red8 = scratch + 6400;  // [128][9]
      float* f1s = scratch + 7552;   // 128
      {  // stage w1c (pad 17) + s2f
        int e = tid & 255, c4 = tid >> 8;
#pragma unroll
        for (int i = 0; i < 4; ++i) {
          int cl = c4 * 4 + i;
          wbuf[e * 17 + cl] = W1[(16 * j + cl) * 256 + e];
        }
      }
      for (int s = tid; s < 2048; s += 1024) s2f[s] = s2g[b * 2048 + s];
      __syncthreads();
      {  // f1 partial: (q, l, cl), e in [q*32, q*32+32)
        int q = tid >> 7, p = tid & 127, l = p >> 4, cl = p & 15;
        const float* xp = s2f + l * 256 + q * 32;
        const float* wp = wbuf + (q * 32) * 17 + cl;
        float a = 0.f;
#pragma unroll 8
        for (int e = 0; e < 32; ++e) a += xp[e] * wp[e * 17];
        red8[p * 9 + q] = a;
      }
      __syncthreads();
      float f1v = 0.f;
      if (tid < 128) {
        float a = b1[16 * j + (tid & 15)];
#pragma unroll
        for (int q = 0; q < 8; ++q) a += red8[tid * 9 + q];
        f1v = fmaxf(a, 0.f);
      }
      // stage w2r (overwrites w1c region; its readers finished at last barrier)
      for (int s = tid; s < 4096; s += 1024) {
        int e = s >> 8, cout = s & 255;
        wbuf[e * 256 + cout] = W2T[(16 * j + e) * 256 + cout];
      }
      if (tid < 128) f1s[tid] = f1v;
      __syncthreads();
      {  // x partial over own 16 e, all couts, 2 slot-rows each
        int lh = tid >> 8, cout = tid & 255;
#pragma unroll
        for (int li = 0; li < 2; ++li) {
          int l = lh + li * 4;
          float a = 0.f;
#pragma unroll
          for (int e = 0; e < 16; ++e) a += f1s[l * 16 + e] * wbuf[e * 256 + cout];
          px[((long)(b * 16 + j) * 8 + l) * 256 + cout] = a;
        }
      }
    }
    grid_sync(cnt, gen, ++rnd);

    // ================= P6: LN + s3 + next Qk (wgs j<8, l=j) =================
    if (j < 8) {
      int l = j;
      float* red4 = scratch;         // 1024
      float* xrow = scratch + 1024;  // 256
      float* s3f = scratch + 1280;   // 256
      float* lnr = scratch + 1536;   // 8
      {
        int q = tid >> 8, cout = tid & 255;
        float a = 0.f;
#pragma unroll
        for (int jj = 0; jj < 4; ++jj)
          a += px[((long)(b * 16 + q * 4 + jj) * 8 + l) * 256 + cout];
        red4[q * 256 + cout] = a;
      }
      __syncthreads();
      if (tid < 256) {
        float x = red4[tid] + red4[256 + tid] + red4[512 + tid] + red4[768 + tid]
                + b2[tid] + s2g[b * 2048 + l * 256 + tid];
        xrow[tid] = x;
        float sr = x, qr = x * x;
#pragma unroll
        for (int m = 1; m < 64; m <<= 1) { sr += __shfl_xor(sr, m); qr += __shfl_xor(qr, m); }
        if ((tid & 63) == 0) { lnr[tid >> 6] = sr; lnr[4 + (tid >> 6)] = qr; }
      }
      __syncthreads();
      if (tid < 256) {
        float m = (lnr[0] + lnr[1] + lnr[2] + lnr[3]) * (1.f / 256.f);
        float v = (lnr[4] + lnr[5] + lnr[6] + lnr[7]) * (1.f / 256.f) - m * m;
        float s3 = (xrow[tid] - m) * rsqrtf(v + 1e-5f) * ln_g[tid] + ln_b[tid];
        s3f[tid] = s3;
        S[(((long)(b * 16) + t) * 8 + l) * 256 + tid] = s3;
        slots[b * 2048 + l * 256 + tid] = s3;
      }
      __syncthreads();
      {
        int q = tid >> 8, cout = tid & 255;
        const float* wq = Wqk + q * 64 * 256 + cout;
        float a = 0.f;
#pragma unroll 8
        for (int e = 0; e < 64; ++e) a += s3f[q * 64 + e] * wq[e * 256];
        red4[q * 256 + cout] = a;
      }
      __syncthreads();
      if (tid < 256)
        QkG[b * 2048 + l * 256 + tid] =
            red4[tid] + red4[256 + tid] + red4[512 + tid] + red4[768 + tid] + bqk[tid];
    }
    grid_sync(cnt, gen, ++rnd);
  }
}

extern "C" void kernel_launch(void* const* d_in, const int* in_sizes, int n_in,
                              void* d_out, int out_size, void* d_ws, size_t ws_size,
                              hipStream_t stream) {
  const float* H    = (const float*)d_in[0];
  const float* eps  = (const float*)d_in[1];
  const float* mu   = (const float*)d_in[2];
  const float* lsig = (const float*)d_in[3];
  const float* Wq   = (const float*)d_in[4];
  const float* bq   = (const float*)d_in[5];
  const float* Wk   = (const float*)d_in[6];
  // d_in[7] = bk: constant per softmax row -> drops out
  const float* Wv   = (const float*)d_in[8];
  const float* bv   = (const float*)d_in[9];
  const float* Wih  = (const float*)d_in[10];
  const float* bih  = (const float*)d_in[11];
  const float* Whh  = (const float*)d_in[12];
  const float* bhh  = (const float*)d_in[13];
  const float* W1   = (const float*)d_in[14];
  const float* b1   = (const float*)d_in[15];
  const float* W2   = (const float*)d_in[16];
  const float* b2   = (const float*)d_in[17];
  const float* ln_g = (const float*)d_in[18];
  const float* ln_b = (const float*)d_in[19];

  float* out = (float*)d_out;
  float* S    = out;                            // [B,K,L,D]
  float* Beta = out + (long)Bn * KK * Ln * Dn;  // [B,K,L,N]

  float* ws = (float*)d_ws;
  float* Wqk   = ws + OFF_WQK;
  float* bqk   = ws + OFF_BQK;
  float* WgiT  = ws + OFF_WGIT;
  float* bgi   = ws + OFF_BGI;
  float* W2T   = ws + OFF_W2T;
  float* Wgi_r = ws + OFF_WGIR;
  float* Whh_r = ws + OFF_WHHR;
  float* slots = ws + OFF_SLOTS;
  float* Qk    = ws + OFF_QK;
  float* pav   = ws + OFF_PAV;
  float* pden  = ws + OFF_PDEN;
  float* s2g   = ws + OFF_S2G;
  float* px    = ws + OFF_PX;
  unsigned* bar = (unsigned*)(ws + OFF_BAR);

  p1_kernel<<<257, 256, 0, stream>>>(Wq, bq, Wk, Wqk, bqk);
  p2_kernel<<<256, 256, 0, stream>>>(Wih, bih, Wv, bv, WgiT, bgi);
  p2b_kernel<<<96, 256, 0, stream>>>(WgiT, Whh, W2, Wgi_r, Whh_r, W2T);
  init_slots_kernel<<<128, 256, 0, stream>>>(eps, mu, lsig, slots, bar);
  qk0_kernel<<<128, 256, 0, stream>>>(Wqk, bqk, slots, Qk);

  fused_kernel<<<256, 1024, 0, stream>>>(
      H, Wgi_r, bgi, Whh_r, bhh, W1, b1, W2T, b2, Wqk, bqk, ln_g, ln_b,
      slots, Qk, S, Beta, pav, pden, s2g, px, bar);
}

// Round 3
// 932.505 us; speedup vs baseline: 3.2588x; 3.2588x over previous
//
#include <hip/hip_runtime.h>
#include <math.h>

// RecurrentSlotEncoder: B=16,K=16,N=1024,D=256,L=8
// Algebra: scores = (slots@Wqk) @ h^T      (no K-projection of h)
//          gi     = (attn@h)·rden @ WgiT + bgi, Wgi = W_ih@Wv  (no V-projection)
// R6 structure (launch-based; persistent/grid-barrier R5 regressed 3x: agent
// fences invalidate per-XCD L2 -> 1.1GB refetch):
// per step = attn (512 wgs) -> gru (256 wgs, K-split GRU partials, LDS-staged
// weight slices) -> chain2a (256 wgs = (b,l,ph): combine -> s2 -> f1-half ->
// FFN2 partial; 16-deep load-batched GEMV loops raise per-CU stream MLP) ->
// chain2b (256 wgs = (b,l,ph): LN -> s3 -> Qk-half). Beta normalization moved
// off the critical path into one post-loop kernel (gru stores 1/den).

#define Bn 16
#define KK 16
#define Nn 1024
#define Dn 256
#define Ln 8

// workspace float offsets
#define OFF_WQK   0          // 256*256   Wqk[d][e]
#define OFF_BQK   65536      // 256
#define OFF_WGIT  65792      // 256*768   WgiT[e][jj] = sum_c Wih[jj][c]*Wv[c][e]
#define OFF_BGI   262400     // 768
#define OFF_WHHT  263168     // 256*768   WhhT[e][jj] = Whh[jj][e]
#define OFF_W1T   459776     // 256*256
#define OFF_W2T   525312     // 256*256
#define OFF_SLOTS 590848     // 128*256
#define OFF_QK    623616     // 128*256
#define OFF_PAV   656384     // [b][tile32][l][256] = 1048576
#define OFF_PDEN  1704960    // [b][tile32][l] = 4096
#define OFF_PG    1709056    // [(b*16+kc)*8+l][1536] = 3145728
#define OFF_PX    4854784    // [b][l][ph][256] = 65536
#define OFF_DENS  4920320    // [t*16+b][8] = 2048
#define OFF_S2G   4922368    // [b][l][256] = 32768

__device__ __forceinline__ float sigmoidf_(float x) { return 1.f / (1.f + __expf(-x)); }

// P1: Wqk[d][e] = sum_a Wq[a][d]*Wk[a][e]; bqk[e] = sum_a bq[a]*Wk[a][e]
__global__ __launch_bounds__(256) void p1_kernel(
    const float* __restrict__ Wq, const float* __restrict__ bq,
    const float* __restrict__ Wk, float* __restrict__ Wqk, float* __restrict__ bqk) {
  int w = blockIdx.x, tid = threadIdx.x;
  if (w < 256) {
    float acc = 0.f;
#pragma unroll 8
    for (int a = 0; a < 256; ++a) acc += Wq[a * 256 + w] * Wk[a * 256 + tid];
    Wqk[w * 256 + tid] = acc;
  } else {
    float acc = 0.f;
#pragma unroll 8
    for (int a = 0; a < 256; ++a) acc += bq[a] * Wk[a * 256 + tid];
    bqk[tid] = acc;
  }
}

// P2: WgiT[e*768+jj] = sum_c Wih[jj][c]*Wv[c][e]; bgi[jj]=bih[jj]+sum_c Wih[jj][c]*bv[c]
__global__ __launch_bounds__(256) void p2_kernel(
    const float* __restrict__ Wih, const float* __restrict__ bih,
    const float* __restrict__ Wv, const float* __restrict__ bv,
    float* __restrict__ WgiT, float* __restrict__ bgi) {
  int d = blockIdx.x, tid = threadIdx.x;
  float a0 = 0.f, a1 = 0.f, a2 = 0.f;
#pragma unroll 4
  for (int c = 0; c < 256; ++c) {
    float wv = Wv[c * 256 + d];  // wave-uniform
    a0 += Wih[tid * 256 + c] * wv;
    a1 += Wih[(tid + 256) * 256 + c] * wv;
    a2 += Wih[(tid + 512) * 256 + c] * wv;
  }
  WgiT[d * 768 + tid] = a0;
  WgiT[d * 768 + 256 + tid] = a1;
  WgiT[d * 768 + 512 + tid] = a2;
  if (d < 3) {
    int jj = d * 256 + tid;
    float s = bih[jj];
    for (int c = 0; c < 256; ++c) s += Wih[jj * 256 + c] * bv[c];
    bgi[jj] = s;
  }
}

// P3: LDS tile transposes: WhhT (768x256 -> 256x768), W1T, W2T (256x256)
__global__ __launch_bounds__(256) void p3_kernel(
    const float* __restrict__ Whh, const float* __restrict__ W1,
    const float* __restrict__ W2, float* __restrict__ WhhT,
    float* __restrict__ W1T, float* __restrict__ W2T) {
  __shared__ float tile[32][33];
  int wg = blockIdx.x, tid = threadIdx.x;
  const float* in; float* out; int R, C, tr, tc;
  if (wg < 192)      { in = Whh; out = WhhT; R = 768; C = 256; wg -= 0;   tr = wg >> 3; tc = wg & 7; }
  else if (wg < 256) { in = W1;  out = W1T;  R = 256; C = 256; wg -= 192; tr = wg >> 3; tc = wg & 7; }
  else               { in = W2;  out = W2T;  R = 256; C = 256; wg -= 256; tr = wg >> 3; tc = wg & 7; }
  int r = tid >> 5, c = tid & 31;
#pragma unroll
  for (int k = 0; k < 4; ++k)
    tile[r + 8 * k][c] = in[(tr * 32 + r + 8 * k) * C + tc * 32 + c];
  __syncthreads();
#pragma unroll
  for (int k = 0; k < 4; ++k)
    out[(tc * 32 + r + 8 * k) * R + tr * 32 + c] = tile[c][r + 8 * k];
}

__global__ __launch_bounds__(256) void init_slots_kernel(
    const float* __restrict__ eps, const float* __restrict__ mu,
    const float* __restrict__ lsig, float* __restrict__ slots) {
  int idx = blockIdx.x * 256 + threadIdx.x;  // 32768
  int r = idx & 2047;
  slots[idx] = mu[r] + expf(lsig[r]) * eps[idx];
}

// Qk = slots @ Wqk + bqk (t=0 only)
__global__ __launch_bounds__(256) void qk0_kernel(
    const float* __restrict__ Wqk, const float* __restrict__ bqk,
    const float* __restrict__ slots, float* __restrict__ Qkout) {
  __shared__ float sl_s[2048];
  int j = blockIdx.x & 7, b = blockIdx.x >> 3, tid = threadIdx.x;
  for (int k = 0; k < 8; ++k) sl_s[tid + k * 256] = slots[b * 2048 + tid + k * 256];
  __syncthreads();
  int l = tid >> 5, ee = j * 32 + (tid & 31);
  float acc = bqk[ee];
#pragma unroll 8
  for (int d = 0; d < 256; ++d) acc += sl_s[l * 256 + d] * Wqk[d * 256 + ee];
  Qkout[b * 2048 + l * 256 + ee] = acc;
}

// Fused attention: wg = (tile32, b), grid (32,16). Stages 32 rows of H in LDS,
// computes exp-scores (unnormalized Beta), per-tile denom, per-tile attn@H.
__global__ __launch_bounds__(256) void attn_kernel(
    const float* __restrict__ H, const float* __restrict__ Qk,
    float* __restrict__ beta_out, float* __restrict__ par_av,
    float* __restrict__ par_den, int t) {
  __shared__ float h_s[32 * 258];
  __shared__ float qk_s[Ln * Dn];
  __shared__ float e_s[256];
  __shared__ float red[256];
  int tile = blockIdx.x, b = blockIdx.y, tid = threadIdx.x;
#pragma unroll
  for (int k = 0; k < 8; ++k) qk_s[tid + k * 256] = Qk[b * 2048 + tid + k * 256];
  const float* Hbase = H + (((long)b * KK + t) * Nn + tile * 32) * Dn;
  const float4* src = (const float4*)Hbase;
#pragma unroll
  for (int k = 0; k < 8; ++k) {
    int idx4 = tid + k * 256;  // 0..2047 coalesced
    int r = idx4 >> 6, d4 = idx4 & 63;
    float4 v = src[idx4];
    float* dst = &h_s[r * 258 + d4 * 4];
    ((float2*)dst)[0] = make_float2(v.x, v.y);
    ((float2*)dst)[1] = make_float2(v.z, v.w);
  }
  __syncthreads();
  int l = tid >> 5, row = tid & 31;
  // phase A: scores
  {
    const float2* hr2 = (const float2*)(&h_s[row * 258]);
    const float2* qr2 = (const float2*)(&qk_s[l * 256]);
    float acc = 0.f;
#pragma unroll 8
    for (int e = 0; e < 128; ++e) {
      float2 hv = hr2[e], qv = qr2[e];
      acc += hv.x * qv.x + hv.y * qv.y;
    }
    float ev = __expf(acc * 0.0625f);  // 1/sqrt(256); no max-sub (|s| small)
    e_s[tid] = ev;
    red[tid] = ev;
    beta_out[(((long)b * KK + t) * Ln + l) * Nn + tile * 32 + row] = ev;
  }
  __syncthreads();
  if (tid < 8) {
    float s = 0.f;
    for (int i = 0; i < 32; ++i) s += red[tid * 32 + i];
    par_den[(b * 32 + tile) * 8 + tid] = s;
  }
  // phase B: av[l] += e[l,row] * h[row, d=tid]
  float av[8];
#pragma unroll
  for (int i = 0; i < 8; ++i) av[i] = 0.f;
  for (int rr = 0; rr < 32; ++rr) {
    float hv = h_s[rr * 258 + tid];
#pragma unroll
    for (int i = 0; i < 8; ++i) av[i] += e_s[i * 32 + rr] * hv;
  }
  long pbase = (long)(b * 32 + tile) * 2048;
#pragma unroll
  for (int i = 0; i < 8; ++i) par_av[pbase + i * 256 + tid] = av[i];
}

// GRU partial kernel: wg = (b, kc16) with b = wid&15 (keeps a batch's wgs on
// one XCD). Each wg stages a 16-row K-slice of WgiT/WhhT in LDS and computes
// partial gi/gh for ALL 8 slot rows of batch b. Stores 1/den to dens_all.
// pg layout: [((b*16+kc)*8+l)*1536 + col]; gi at col c+{0,256,512}, gh at 768+...
__global__ __launch_bounds__(1024) void gru_kernel(
    const float* __restrict__ WgiT, const float* __restrict__ WhhT,
    const float* __restrict__ par_av, const float* __restrict__ par_den,
    const float* __restrict__ slots, float* __restrict__ pg,
    float* __restrict__ dens_all, int t) {
  __shared__ float w_s[16 * 768];  // 48KB staged weight slice (reused gi -> gh)
  __shared__ float rupd[8][128];
  __shared__ float upd_s[128];     // [l*16+e], scaled by 1/den
  __shared__ float sl_s[128];      // slots slice [l*16+e]
  __shared__ float den_s[8];
  int b = blockIdx.x & 15, kc = blockIdx.x >> 4;
  int tid = threadIdx.x;

  // region 1: stage WgiT slice; par_av partial reduce; den; slots slice
  const float4* wsrc = (const float4*)(WgiT + kc * 12288);
  float4 wv0 = wsrc[tid], wv1 = wsrc[tid + 1024], wv2 = wsrc[tid + 2048];
  {
    int g = tid >> 7, le = tid & 127;       // le = l*16+e
    int l = le >> 4, e = le & 15;
    float ps = 0.f;
    long base = ((long)(b * 32)) * 2048 + l * 256 + kc * 16 + e;
#pragma unroll
    for (int i = 0; i < 4; ++i) ps += par_av[base + (long)(g * 4 + i) * 2048];
    rupd[g][le] = ps;
  }
  if (tid < 256) {
    int ll = tid >> 5, tl = tid & 31;
    float dv = par_den[(b * 32 + tl) * 8 + ll];
#pragma unroll
    for (int m = 1; m < 32; m <<= 1) dv += __shfl_xor(dv, m);
    if (tl == 0) den_s[ll] = 1.f / dv;
  }
  if (tid < 128) sl_s[tid] = slots[b * 2048 + (tid >> 4) * 256 + kc * 16 + (tid & 15)];
  ((float4*)w_s)[tid] = wv0;
  ((float4*)w_s)[tid + 1024] = wv1;
  ((float4*)w_s)[tid + 2048] = wv2;
  __syncthreads();

  // region 2: finalize scaled upd; store 1/den (once per batch)
  if (kc == 0 && tid < 8) dens_all[(t * 16 + b) * 8 + tid] = den_s[tid];
  if (tid < 128) {
    float s = 0.f;
#pragma unroll
    for (int g = 0; g < 8; ++g) s += rupd[g][tid];
    upd_s[tid] = s * den_s[tid >> 4];
  }
  __syncthreads();

  // region 3: gi partials. thread = (l4 = tid>>8, cb = tid&255) covers rows
  // {l4, l4+4} and cols {cb, cb+256, cb+512}: each LDS weight read serves 2 rows.
  int l4 = tid >> 8, cb = tid & 255;
  long pb0 = ((long)(b * 16 + kc) * 8 + l4) * 1536;
  long pb1 = ((long)(b * 16 + kc) * 8 + l4 + 4) * 1536;
  {
    float a0 = 0.f, a1 = 0.f, a2 = 0.f, a3 = 0.f, a4 = 0.f, a5 = 0.f;
#pragma unroll
    for (int e = 0; e < 16; ++e) {
      float u0 = upd_s[l4 * 16 + e];
      float u1 = upd_s[(l4 + 4) * 16 + e];
      float w0 = w_s[e * 768 + cb];
      float w1 = w_s[e * 768 + 256 + cb];
      float w2 = w_s[e * 768 + 512 + cb];
      a0 += u0 * w0; a1 += u0 * w1; a2 += u0 * w2;
      a3 += u1 * w0; a4 += u1 * w1; a5 += u1 * w2;
    }
    pg[pb0 + cb] = a0; pg[pb0 + 256 + cb] = a1; pg[pb0 + 512 + cb] = a2;
    pg[pb1 + cb] = a3; pg[pb1 + 256 + cb] = a4; pg[pb1 + 512 + cb] = a5;
  }
  __syncthreads();
  // region 4: stage WhhT slice into same LDS
  {
    const float4* hsrc = (const float4*)(WhhT + kc * 12288);
    ((float4*)w_s)[tid] = hsrc[tid];
    ((float4*)w_s)[tid + 1024] = hsrc[tid + 1024];
    ((float4*)w_s)[tid + 2048] = hsrc[tid + 2048];
  }
  __syncthreads();
  // region 5: gh partials (cols 768..1535)
  {
    float a0 = 0.f, a1 = 0.f, a2 = 0.f, a3 = 0.f, a4 = 0.f, a5 = 0.f;
#pragma unroll
    for (int e = 0; e < 16; ++e) {
      float s0 = sl_s[l4 * 16 + e];
      float s1 = sl_s[(l4 + 4) * 16 + e];
      float w0 = w_s[e * 768 + cb];
      float w1 = w_s[e * 768 + 256 + cb];
      float w2 = w_s[e * 768 + 512 + cb];
      a0 += s0 * w0; a1 += s0 * w1; a2 += s0 * w2;
      a3 += s1 * w0; a4 += s1 * w1; a5 += s1 * w2;
    }
    pg[pb0 + 768 + cb] = a0; pg[pb0 + 1024 + cb] = a1; pg[pb0 + 1280 + cb] = a2;
    pg[pb1 + 768 + cb] = a3; pg[pb1 + 1024 + cb] = a4; pg[pb1 + 1280 + cb] = a5;
  }
}

// chain2a: wg = (b, l, ph), 256 wgs x 1024 thr. combine pg -> GRU nonlin -> s2
// (ph==0 writes) -> f1 for h in ph-half -> FFN2 partial px[b][l][ph][cout].
// All global GEMV loops are 16-deep load-batched for memory-level parallelism.
__global__ __launch_bounds__(1024) void chain2a_kernel(
    const float* __restrict__ pg, const float* __restrict__ bgi,
    const float* __restrict__ bhh,
    const float* __restrict__ W1T, const float* __restrict__ b1,
    const float* __restrict__ W2T,
    const float* __restrict__ slots, float* __restrict__ s2g,
    float* __restrict__ px) {
  __shared__ float gsum[1536];
  __shared__ float s2_s[256];
  __shared__ float f1s[128];
  __shared__ float red8[128 * 9];
  __shared__ float red4[1024];
  int wid = blockIdx.x;
  int b = wid & 15, l = (wid >> 4) & 7, ph = wid >> 7;
  int tid = threadIdx.x;

  // combine GRU partials over 16 kc slices (16 loads in flight)
  for (int col = tid; col < 1536; col += 1024) {
    float v[16];
#pragma unroll
    for (int j = 0; j < 16; ++j) v[j] = pg[((long)(b * 16 + j) * 8 + l) * 1536 + col];
    float a = 0.f;
#pragma unroll
    for (int j = 0; j < 16; ++j) a += v[j];
    gsum[col] = a;
  }
  __syncthreads();
  if (tid < 256) {
    int c = tid;
    float r = sigmoidf_(gsum[c] + bgi[c] + gsum[768 + c] + bhh[c]);
    float z = sigmoidf_(gsum[256 + c] + bgi[256 + c] + gsum[1024 + c] + bhh[256 + c]);
    float n = tanhf(gsum[512 + c] + bgi[512 + c] + r * (gsum[1280 + c] + bhh[512 + c]));
    float s2 = (1.f - z) * n + z * slots[b * 2048 + l * 256 + c];
    s2_s[c] = s2;
    if (ph == 0) s2g[b * 2048 + l * 256 + c] = s2;
  }
  __syncthreads();
  // f1 half: thread (kc = tid>>7 in [0,8), h = tid&127), e = kc*32 .. +32
  {
    int kc = tid >> 7, h = tid & 127;
    const float* wp = W1T + (kc * 32) * 256 + ph * 128 + h;
    const float* sp = s2_s + kc * 32;
    float acc = 0.f;
#pragma unroll
    for (int g = 0; g < 2; ++g) {
      float w[16];
#pragma unroll
      for (int i = 0; i < 16; ++i) w[i] = wp[(g * 16 + i) * 256];
#pragma unroll
      for (int i = 0; i < 16; ++i) acc += sp[g * 16 + i] * w[i];
    }
    red8[h * 9 + kc] = acc;
  }
  __syncthreads();
  if (tid < 128) {
    float a = b1[ph * 128 + tid];
#pragma unroll
    for (int kc = 0; kc < 8; ++kc) a += red8[tid * 9 + kc];
    f1s[tid] = fmaxf(a, 0.f);
  }
  __syncthreads();
  // FFN2 partial over own h-half: thread (q = tid>>8 in [0,4), c = tid&255)
  {
    int q = tid >> 8, c = tid & 255;
    const float* wp = W2T + (ph * 128 + q * 32) * 256 + c;
    const float* fp = f1s + q * 32;
    float acc = 0.f;
#pragma unroll
    for (int g = 0; g < 2; ++g) {
      float w[16];
#pragma unroll
      for (int i = 0; i < 16; ++i) w[i] = wp[(g * 16 + i) * 256];
#pragma unroll
      for (int i = 0; i < 16; ++i) acc += fp[g * 16 + i] * w[i];
    }
    red4[q * 256 + c] = acc;
  }
  __syncthreads();
  if (tid < 256)
    px[((long)(b * 8 + l) * 2 + ph) * 256 + tid] =
        red4[tid] + red4[256 + tid] + red4[512 + tid] + red4[768 + tid];
}

// chain2b: wg = (b, l, ph), 256 wgs x 1024 thr. x = px0+px1+b2+s2 -> LN -> s3
// (ph==0 writes S/slots) -> Qk for couts in ph-half (load-batched Wqk).
__global__ __launch_bounds__(1024) void chain2b_kernel(
    const float* __restrict__ px, const float* __restrict__ b2,
    const float* __restrict__ ln_g, const float* __restrict__ ln_b,
    const float* __restrict__ Wqk, const float* __restrict__ bqk,
    const float* __restrict__ s2g, float* __restrict__ slots,
    float* __restrict__ S, float* __restrict__ QkG, int t) {
  __shared__ float s3_s[256];
  __shared__ float red8[128 * 9];
  __shared__ float lnr[8];
  int wid = blockIdx.x;
  int b = wid & 15, l = (wid >> 4) & 7, ph = wid >> 7;
  int tid = threadIdx.x;
  if (tid < 256) {
    long pb = (long)(b * 8 + l) * 2 * 256;
    float x = px[pb + tid] + px[pb + 256 + tid] + b2[tid] + s2g[b * 2048 + l * 256 + tid];
    s3_s[tid] = x;
    float sr = x, qr = x * x;
#pragma unroll
    for (int m = 1; m < 64; m <<= 1) { sr += __shfl_xor(sr, m); qr += __shfl_xor(qr, m); }
    if ((tid & 63) == 0) { lnr[tid >> 6] = sr; lnr[4 + (tid >> 6)] = qr; }
  }
  __syncthreads();
  if (tid < 256) {
    float m = (lnr[0] + lnr[1] + lnr[2] + lnr[3]) * (1.f / 256.f);
    float v = (lnr[4] + lnr[5] + lnr[6] + lnr[7]) * (1.f / 256.f) - m * m;
    float s3 = (s3_s[tid] - m) * rsqrtf(v + 1e-5f) * ln_g[tid] + ln_b[tid];
    s3_s[tid] = s3;  // own element only: no race
    if (ph == 0) {
      S[(((long)(b * 16) + t) * 8 + l) * 256 + tid] = s3;
      slots[b * 2048 + l * 256 + tid] = s3;
    }
  }
  __syncthreads();
  // Qk half: thread (kc = tid>>7 in [0,8), c = tid&127), e = kc*32 .. +32
  {
    int kc = tid >> 7, c = tid & 127;
    const float* wp = Wqk + (kc * 32) * 256 + ph * 128 + c;
    const float* sp = s3_s + kc * 32;
    float acc = 0.f;
#pragma unroll
    for (int g = 0; g < 2; ++g) {
      float w[16];
#pragma unroll
      for (int i = 0; i < 16; ++i) w[i] = wp[(g * 16 + i) * 256];
#pragma unroll
      for (int i = 0; i < 16; ++i) acc += sp[g * 16 + i] * w[i];
    }
    red8[c * 9 + kc] = acc;
  }
  __syncthreads();
  if (tid < 128) {
    float a = bqk[ph * 128 + tid];
#pragma unroll
    for (int kc = 0; kc < 8; ++kc) a += red8[tid * 9 + kc];
    QkG[b * 2048 + l * 256 + ph * 128 + tid] = a;
  }
}

// Post-pass: Beta[b,t,l,:] *= dens_all[t*16+b][l] for all 16 steps at once.
__global__ __launch_bounds__(1024) void beta_norm_kernel(
    const float* __restrict__ dens_all, float* __restrict__ Beta) {
  int wid = blockIdx.x;
  int b = wid >> 4, t = wid & 15;
  int tid = threadIdx.x;
  long base = (((long)b * 16) + t) * 8192;
#pragma unroll
  for (int i = 0; i < 8; ++i) {
    int idx = i * 1024 + tid;
    int l = idx >> 10;
    Beta[base + idx] *= dens_all[(t * 16 + b) * 8 + l];
  }
}

extern "C" void kernel_launch(void* const* d_in, const int* in_sizes, int n_in,
                              void* d_out, int out_size, void* d_ws, size_t ws_size,
                              hipStream_t stream) {
  const float* H    = (const float*)d_in[0];
  const float* eps  = (const float*)d_in[1];
  const float* mu   = (const float*)d_in[2];
  const float* lsig = (const float*)d_in[3];
  const float* Wq   = (const float*)d_in[4];
  const float* bq   = (const float*)d_in[5];
  const float* Wk   = (const float*)d_in[6];
  // d_in[7] = bk: constant per softmax row -> drops out
  const float* Wv   = (const float*)d_in[8];
  const float* bv   = (const float*)d_in[9];
  const float* Wih  = (const float*)d_in[10];
  const float* bih  = (const float*)d_in[11];
  const float* Whh  = (const float*)d_in[12];
  const float* bhh  = (const float*)d_in[13];
  const float* W1   = (const float*)d_in[14];
  const float* b1   = (const float*)d_in[15];
  const float* W2   = (const float*)d_in[16];
  const float* b2   = (const float*)d_in[17];
  const float* ln_g = (const float*)d_in[18];
  const float* ln_b = (const float*)d_in[19];

  float* out = (float*)d_out;
  float* S    = out;                            // [B,K,L,D]
  float* Beta = out + (long)Bn * KK * Ln * Dn;  // [B,K,L,N]

  float* ws = (float*)d_ws;
  float* Wqk   = ws + OFF_WQK;
  float* bqk   = ws + OFF_BQK;
  float* WgiT  = ws + OFF_WGIT;
  float* bgi   = ws + OFF_BGI;
  float* WhhT  = ws + OFF_WHHT;
  float* W1T   = ws + OFF_W1T;
  float* W2T   = ws + OFF_W2T;
  float* slots = ws + OFF_SLOTS;
  float* Qk    = ws + OFF_QK;
  float* pav   = ws + OFF_PAV;
  float* pden  = ws + OFF_PDEN;
  float* pg    = ws + OFF_PG;
  float* px    = ws + OFF_PX;
  float* dens  = ws + OFF_DENS;
  float* s2g   = ws + OFF_S2G;

  p1_kernel<<<257, 256, 0, stream>>>(Wq, bq, Wk, Wqk, bqk);
  p2_kernel<<<256, 256, 0, stream>>>(Wih, bih, Wv, bv, WgiT, bgi);
  p3_kernel<<<320, 256, 0, stream>>>(Whh, W1, W2, WhhT, W1T, W2T);
  init_slots_kernel<<<128, 256, 0, stream>>>(eps, mu, lsig, slots);
  qk0_kernel<<<128, 256, 0, stream>>>(Wqk, bqk, slots, Qk);

  for (int t = 0; t < KK; ++t) {
    attn_kernel<<<dim3(32, 16), 256, 0, stream>>>(H, Qk, Beta, pav, pden, t);
    gru_kernel<<<256, 1024, 0, stream>>>(WgiT, WhhT, pav, pden, slots, pg, dens, t);
    chain2a_kernel<<<256, 1024, 0, stream>>>(pg, bgi, bhh, W1T, b1, W2T, slots, s2g, px);
    chain2b_kernel<<<256, 1024, 0, stream>>>(px, b2, ln_g, ln_b, Wqk, bqk,
                                             s2g, slots, S, Qk, t);
  }
  beta_norm_kernel<<<256, 1024, 0, stream>>>(dens, Beta);
}

// Round 5
// 888.385 us; speedup vs baseline: 3.4207x; 1.0497x over previous
//
#include <hip/hip_runtime.h>
#include <math.h>

// RecurrentSlotEncoder: B=16,K=16,N=1024,D=256,L=8
// Algebra: scores = (slots@Wqk) @ h^T      (no K-projection of h)
//          gi     = (attn@h)·rden @ WgiT + bgi, Wgi = W_ih@Wv  (no V-projection)
// R7 structure: 3 launches/step (was 4):
//   attn (512 wgs, reg-tiled phase A: float4 LDS, 3x fewer LDS instrs)
//   gru  (256 wgs, K-split GRU partials, LDS-staged weight slices)
//   chainm (256 wgs = (b,l,ph)): pg-combine -> GRU nonlin -> FULL f1 -> FULL x
//          -> LN -> s3 -> Qk-half. Both ph wgs redundantly compute f1/x/LN
//          (weights L2-resident; redundancy cheaper than a launch + px trip).
//          slots ping-pong: both ph read slots_cur, ph0 writes slots_nxt.
// Prologue merged into 1 kernel (961 wgs, branch by blockIdx) + qk0.
// Beta normalization post-loop (gru stores 1/den per step).

#define Bn 16
#define KK 16
#define Nn 1024
#define Dn 256
#define Ln 8

// workspace float offsets
#define OFF_WQK   0          // 256*256   Wqk[d][e]
#define OFF_BQK   65536      // 256
#define OFF_WGIT  65792      // 256*768   WgiT[e][jj] = sum_c Wih[jj][c]*Wv[c][e]
#define OFF_BGI   262400     // 768
#define OFF_WHHT  263168     // 256*768   WhhT[e][jj] = Whh[jj][e]
#define OFF_W1T   459776     // 256*256
#define OFF_W2T   525312     // 256*256
#define OFF_SLOTS 590848     // 2 x 128*256 ping-pong
#define OFF_QK    656384     // 128*256
#define OFF_PAV   689152     // [b][tile32][l][256] = 1048576
#define OFF_PDEN  1737728    // [b][tile32][l] = 4096
#define OFF_PG    1741824    // [(b*16+kc)*8+l][1536] = 3145728
#define OFF_DENS  4887552    // [t*16+b][8] = 2048

__device__ __forceinline__ float sigmoidf_(float x) { return 1.f / (1.f + __expf(-x)); }

// Merged prologue: wg 0..256 = p1 (Wqk/bqk), 257..512 = p2 (WgiT/bgi),
// 513..832 = p3 transposes, 833..960 = init_slots.
__global__ __launch_bounds__(256) void prologue_kernel(
    const float* __restrict__ Wq, const float* __restrict__ bq,
    const float* __restrict__ Wk,
    const float* __restrict__ Wih, const float* __restrict__ bih,
    const float* __restrict__ Wv, const float* __restrict__ bv,
    const float* __restrict__ Whh, const float* __restrict__ W1,
    const float* __restrict__ W2,
    const float* __restrict__ eps, const float* __restrict__ mu,
    const float* __restrict__ lsig,
    float* __restrict__ Wqk, float* __restrict__ bqk,
    float* __restrict__ WgiT, float* __restrict__ bgi,
    float* __restrict__ WhhT, float* __restrict__ W1T, float* __restrict__ W2T,
    float* __restrict__ slots) {
  __shared__ float tile[32][33];
  int wg = blockIdx.x, tid = threadIdx.x;
  if (wg < 257) {
    int w = wg;
    if (w < 256) {
      float acc = 0.f;
#pragma unroll 8
      for (int a = 0; a < 256; ++a) acc += Wq[a * 256 + w] * Wk[a * 256 + tid];
      Wqk[w * 256 + tid] = acc;
    } else {
      float acc = 0.f;
#pragma unroll 8
      for (int a = 0; a < 256; ++a) acc += bq[a] * Wk[a * 256 + tid];
      bqk[tid] = acc;
    }
  } else if (wg < 513) {
    int d = wg - 257;
    float a0 = 0.f, a1 = 0.f, a2 = 0.f;
#pragma unroll 4
    for (int c = 0; c < 256; ++c) {
      float wv = Wv[c * 256 + d];  // wave-uniform
      a0 += Wih[tid * 256 + c] * wv;
      a1 += Wih[(tid + 256) * 256 + c] * wv;
      a2 += Wih[(tid + 512) * 256 + c] * wv;
    }
    WgiT[d * 768 + tid] = a0;
    WgiT[d * 768 + 256 + tid] = a1;
    WgiT[d * 768 + 512 + tid] = a2;
    if (d < 3) {
      int jj = d * 256 + tid;
      float s = bih[jj];
      for (int c = 0; c < 256; ++c) s += Wih[jj * 256 + c] * bv[c];
      bgi[jj] = s;
    }
  } else if (wg < 833) {
    int sub = wg - 513;
    const float* in; float* out; int R, C, tr, tc;
    if (sub < 192)      { in = Whh; out = WhhT; R = 768; C = 256; tr = sub >> 3; tc = sub & 7; }
    else if (sub < 256) { in = W1;  out = W1T;  R = 256; C = 256; sub -= 192; tr = sub >> 3; tc = sub & 7; }
    else                { in = W2;  out = W2T;  R = 256; C = 256; sub -= 256; tr = sub >> 3; tc = sub & 7; }
    int r = tid >> 5, c = tid & 31;
#pragma unroll
    for (int k = 0; k < 4; ++k)
      tile[r + 8 * k][c] = in[(tr * 32 + r + 8 * k) * C + tc * 32 + c];
    __syncthreads();
#pragma unroll
    for (int k = 0; k < 4; ++k)
      out[(tc * 32 + r + 8 * k) * R + tr * 32 + c] = tile[c][r + 8 * k];
  } else {
    int idx = (wg - 833) * 256 + tid;  // 0..32767
    int r = idx & 2047;
    slots[idx] = mu[r] + expf(lsig[r]) * eps[idx];
  }
}

// Qk = slots @ Wqk + bqk (t=0 only)
__global__ __launch_bounds__(256) void qk0_kernel(
    const float* __restrict__ Wqk, const float* __restrict__ bqk,
    const float* __restrict__ slots, float* __restrict__ Qkout) {
  __shared__ float sl_s[2048];
  int j = blockIdx.x & 7, b = blockIdx.x >> 3, tid = threadIdx.x;
  for (int k = 0; k < 8; ++k) sl_s[tid + k * 256] = slots[b * 2048 + tid + k * 256];
  __syncthreads();
  int l = tid >> 5, ee = j * 32 + (tid & 31);
  float acc = bqk[ee];
#pragma unroll 8
  for (int d = 0; d < 256; ++d) acc += sl_s[l * 256 + d] * Wqk[d * 256 + ee];
  Qkout[b * 2048 + l * 256 + ee] = acc;
}

// Fused attention: wg = (tile32, b), grid (32,16). Stages 32 rows of H in LDS.
// Phase A reg-tiled: thread (eg8, lh2, rq16) = 2 rows x 4 l x 32-e chunk via
// float4 LDS reads (48 b128/thread vs 256 b64); eg-partials reduced in LDS.
// Phase B: es2[row][8] -> 2 broadcast b128 per row.
__global__ __launch_bounds__(256) void attn_kernel(
    const float* __restrict__ H, const float* __restrict__ Qk,
    float* __restrict__ beta_out, float* __restrict__ par_av,
    float* __restrict__ par_den, int t) {
  __shared__ float h_s[32 * 260];   // stride 260 floats (1040B, 16B-aligned)
  __shared__ float qk_s[8 * 260];
  __shared__ float red_a[8 * 256];  // [eg][l*32+row]
  __shared__ float es2[32 * 8];     // [row][l]
  __shared__ float red[256];        // [l*32+row] for den
  int tile = blockIdx.x, b = blockIdx.y, tid = threadIdx.x;
#pragma unroll
  for (int k = 0; k < 8; ++k) {
    int idx = tid + k * 256, l = idx >> 8, e = idx & 255;
    qk_s[l * 260 + e] = Qk[b * 2048 + idx];
  }
  const float4* src = (const float4*)(H + (((long)b * KK + t) * Nn + tile * 32) * Dn);
#pragma unroll
  for (int k = 0; k < 8; ++k) {
    int idx4 = tid + k * 256, r = idx4 >> 6, d4 = idx4 & 63;
    *(float4*)(&h_s[r * 260 + d4 * 4]) = src[idx4];
  }
  __syncthreads();
  // phase A
  {
    int eg = tid >> 5, lh = (tid >> 4) & 1, rq = tid & 15;
    float4 hA[8], hB[8];
    const float4* ha = (const float4*)(&h_s[(rq * 2) * 260 + eg * 32]);
    const float4* hb = (const float4*)(&h_s[(rq * 2 + 1) * 260 + eg * 32]);
#pragma unroll
    for (int i = 0; i < 8; ++i) { hA[i] = ha[i]; hB[i] = hb[i]; }
    float acc[4][2] = {{0.f, 0.f}, {0.f, 0.f}, {0.f, 0.f}, {0.f, 0.f}};
#pragma unroll
    for (int li = 0; li < 4; ++li) {
      const float4* qv = (const float4*)(&qk_s[(lh * 4 + li) * 260 + eg * 32]);
#pragma unroll
      for (int i = 0; i < 8; ++i) {
        float4 qq = qv[i];
        acc[li][0] += qq.x * hA[i].x + qq.y * hA[i].y + qq.z * hA[i].z + qq.w * hA[i].w;
        acc[li][1] += qq.x * hB[i].x + qq.y * hB[i].y + qq.z * hB[i].z + qq.w * hB[i].w;
      }
    }
#pragma unroll
    for (int li = 0; li < 4; ++li) {
      red_a[eg * 256 + (lh * 4 + li) * 32 + rq * 2] = acc[li][0];
      red_a[eg * 256 + (lh * 4 + li) * 32 + rq * 2 + 1] = acc[li][1];
    }
  }
  __syncthreads();
  // reduce eg-partials -> exp -> Beta + den staging
  {
    int l = tid >> 5, row = tid & 31;
    float a = 0.f;
#pragma unroll
    for (int eg = 0; eg < 8; ++eg) a += red_a[eg * 256 + l * 32 + row];
    float ev = __expf(a * 0.0625f);  // 1/sqrt(256); no max-sub (|s| small)
    es2[row * 8 + l] = ev;
    red[tid] = ev;
    beta_out[(((long)b * KK + t) * Ln + l) * Nn + tile * 32 + row] = ev;
  }
  __syncthreads();
  if (tid < 8) {
    float s = 0.f;
    for (int i = 0; i < 32; ++i) s += red[tid * 32 + i];
    par_den[(b * 32 + tile) * 8 + tid] = s;
  }
  // phase B: av[l] += e[row][l] * h[row][d=tid]
  float av[8] = {0.f, 0.f, 0.f, 0.f, 0.f, 0.f, 0.f, 0.f};
  for (int rr = 0; rr < 32; ++rr) {
    float hv = h_s[rr * 260 + tid];
    float4 ea = *(const float4*)(&es2[rr * 8]);
    float4 eb = *(const float4*)(&es2[rr * 8 + 4]);
    av[0] += ea.x * hv; av[1] += ea.y * hv; av[2] += ea.z * hv; av[3] += ea.w * hv;
    av[4] += eb.x * hv; av[5] += eb.y * hv; av[6] += eb.z * hv; av[7] += eb.w * hv;
  }
  long pbase = (long)(b * 32 + tile) * 2048;
#pragma unroll
  for (int i = 0; i < 8; ++i) par_av[pbase + i * 256 + tid] = av[i];
}

// GRU partial kernel: wg = (b, kc16), b = wid&15. Stages 16-row K-slice of
// WgiT/WhhT in LDS, computes partial gi/gh for all 8 slot rows of batch b.
// Stores 1/den once per (t,b). Reads slots_cur (ping-pong).
__global__ __launch_bounds__(1024) void gru_kernel(
    const float* __restrict__ WgiT, const float* __restrict__ WhhT,
    const float* __restrict__ par_av, const float* __restrict__ par_den,
    const float* __restrict__ slots_cur, float* __restrict__ pg,
    float* __restrict__ dens_all, int t) {
  __shared__ float w_s[16 * 768];  // 48KB staged slice (reused gi -> gh)
  __shared__ float rupd[8][128];
  __shared__ float upd_s[128];
  __shared__ float sl_s[128];
  __shared__ float den_s[8];
  int b = blockIdx.x & 15, kc = blockIdx.x >> 4;
  int tid = threadIdx.x;

  const float4* wsrc = (const float4*)(WgiT + kc * 12288);
  float4 wv0 = wsrc[tid], wv1 = wsrc[tid + 1024], wv2 = wsrc[tid + 2048];
  {
    int g = tid >> 7, le = tid & 127;
    int l = le >> 4, e = le & 15;
    float ps = 0.f;
    long base = ((long)(b * 32)) * 2048 + l * 256 + kc * 16 + e;
#pragma unroll
    for (int i = 0; i < 4; ++i) ps += par_av[base + (long)(g * 4 + i) * 2048];
    rupd[g][le] = ps;
  }
  if (tid < 256) {
    int ll = tid >> 5, tl = tid & 31;
    float dv = par_den[(b * 32 + tl) * 8 + ll];
#pragma unroll
    for (int m = 1; m < 32; m <<= 1) dv += __shfl_xor(dv, m);
    if (tl == 0) den_s[ll] = 1.f / dv;
  }
  if (tid < 128) sl_s[tid] = slots_cur[b * 2048 + (tid >> 4) * 256 + kc * 16 + (tid & 15)];
  ((float4*)w_s)[tid] = wv0;
  ((float4*)w_s)[tid + 1024] = wv1;
  ((float4*)w_s)[tid + 2048] = wv2;
  __syncthreads();

  if (kc == 0 && tid < 8) dens_all[(t * 16 + b) * 8 + tid] = den_s[tid];
  if (tid < 128) {
    float s = 0.f;
#pragma unroll
    for (int g = 0; g < 8; ++g) s += rupd[g][tid];
    upd_s[tid] = s * den_s[tid >> 4];
  }
  __syncthreads();

  int l4 = tid >> 8, cb = tid & 255;
  long pb0 = ((long)(b * 16 + kc) * 8 + l4) * 1536;
  long pb1 = ((long)(b * 16 + kc) * 8 + l4 + 4) * 1536;
  {
    float a0 = 0.f, a1 = 0.f, a2 = 0.f, a3 = 0.f, a4 = 0.f, a5 = 0.f;
#pragma unroll
    for (int e = 0; e < 16; ++e) {
      float u0 = upd_s[l4 * 16 + e];
      float u1 = upd_s[(l4 + 4) * 16 + e];
      float w0 = w_s[e * 768 + cb];
      float w1 = w_s[e * 768 + 256 + cb];
      float w2 = w_s[e * 768 + 512 + cb];
      a0 += u0 * w0; a1 += u0 * w1; a2 += u0 * w2;
      a3 += u1 * w0; a4 += u1 * w1; a5 += u1 * w2;
    }
    pg[pb0 + cb] = a0; pg[pb0 + 256 + cb] = a1; pg[pb0 + 512 + cb] = a2;
    pg[pb1 + cb] = a3; pg[pb1 + 256 + cb] = a4; pg[pb1 + 512 + cb] = a5;
  }
  __syncthreads();
  {
    const float4* hsrc = (const float4*)(WhhT + kc * 12288);
    ((float4*)w_s)[tid] = hsrc[tid];
    ((float4*)w_s)[tid + 1024] = hsrc[tid + 1024];
    ((float4*)w_s)[tid + 2048] = hsrc[tid + 2048];
  }
  __syncthreads();
  {
    float a0 = 0.f, a1 = 0.f, a2 = 0.f, a3 = 0.f, a4 = 0.f, a5 = 0.f;
#pragma unroll
    for (int e = 0; e < 16; ++e) {
      float s0 = sl_s[l4 * 16 + e];
      float s1 = sl_s[(l4 + 4) * 16 + e];
      float w0 = w_s[e * 768 + cb];
      float w1 = w_s[e * 768 + 256 + cb];
      float w2 = w_s[e * 768 + 512 + cb];
      a0 += s0 * w0; a1 += s0 * w1; a2 += s0 * w2;
      a3 += s1 * w0; a4 += s1 * w1; a5 += s1 * w2;
    }
    pg[pb0 + 768 + cb] = a0; pg[pb0 + 1024 + cb] = a1; pg[pb0 + 1280 + cb] = a2;
    pg[pb1 + 768 + cb] = a3; pg[pb1 + 1024 + cb] = a4; pg[pb1 + 1280 + cb] = a5;
  }
}

// chainm: wg = (b, l, ph), 256 wgs x 1024 thr. pg-combine -> GRU nonlin ->
// full f1 -> full x -> LN -> s3 (ph0 writes S/slots_nxt) -> Qk ph-half.
// 16-deep load-batched GEMV loops; weights L2-resident.
__global__ __launch_bounds__(1024) void chainm_kernel(
    const float* __restrict__ pg, const float* __restrict__ bgi,
    const float* __restrict__ bhh,
    const float* __restrict__ W1T, const float* __restrict__ b1,
    const float* __restrict__ W2T, const float* __restrict__ b2,
    const float* __restrict__ Wqk, const float* __restrict__ bqk,
    const float* __restrict__ ln_g, const float* __restrict__ ln_b,
    const float* __restrict__ slots_cur, float* __restrict__ slots_nxt,
    float* __restrict__ S, float* __restrict__ QkG, int t) {
  __shared__ float gsum[1536];
  __shared__ float s2_s[256], f1s[256], s3_s[256];
  __shared__ float red4[1024];
  __shared__ float red8[128 * 9];
  __shared__ float lnr[8];
  int wid = blockIdx.x;
  int b = wid & 15, l = (wid >> 4) & 7, ph = wid >> 7;
  int tid = threadIdx.x, q = tid >> 8, c = tid & 255;

  // combine GRU partials over 16 kc slices (16 loads in flight)
  for (int col = tid; col < 1536; col += 1024) {
    float v[16];
#pragma unroll
    for (int j = 0; j < 16; ++j) v[j] = pg[((long)(b * 16 + j) * 8 + l) * 1536 + col];
    float a = 0.f;
#pragma unroll
    for (int j = 0; j < 16; ++j) a += v[j];
    gsum[col] = a;
  }
  __syncthreads();
  if (tid < 256) {
    float r = sigmoidf_(gsum[c] + bgi[c] + gsum[768 + c] + bhh[c]);
    float z = sigmoidf_(gsum[256 + c] + bgi[256 + c] + gsum[1024 + c] + bhh[256 + c]);
    float n = tanhf(gsum[512 + c] + bgi[512 + c] + r * (gsum[1280 + c] + bhh[512 + c]));
    s2_s[c] = (1.f - z) * n + z * slots_cur[b * 2048 + l * 256 + c];
  }
  __syncthreads();
  // f1 full: thread (q,c), e = q*64..+64
  {
    const float* wp = W1T + (q * 64) * 256 + c;
    const float* sp = s2_s + q * 64;
    float acc = 0.f;
#pragma unroll
    for (int g = 0; g < 4; ++g) {
      float w[16];
#pragma unroll
      for (int i = 0; i < 16; ++i) w[i] = wp[(g * 16 + i) * 256];
#pragma unroll
      for (int i = 0; i < 16; ++i) acc += sp[g * 16 + i] * w[i];
    }
    red4[q * 256 + c] = acc;
  }
  __syncthreads();
  if (tid < 256)
    f1s[c] = fmaxf(red4[c] + red4[256 + c] + red4[512 + c] + red4[768 + c] + b1[c], 0.f);
  __syncthreads();
  // x full: thread (q,c), e = q*64..+64
  {
    const float* wp = W2T + (q * 64) * 256 + c;
    const float* fp = f1s + q * 64;
    float acc = 0.f;
#pragma unroll
    for (int g = 0; g < 4; ++g) {
      float w[16];
#pragma unroll
      for (int i = 0; i < 16; ++i) w[i] = wp[(g * 16 + i) * 256];
#pragma unroll
      for (int i = 0; i < 16; ++i) acc += fp[g * 16 + i] * w[i];
    }
    red4[q * 256 + c] = acc;
  }
  __syncthreads();
  if (tid < 256) {
    float x = red4[c] + red4[256 + c] + red4[512 + c] + red4[768 + c] + b2[c] + s2_s[c];
    s3_s[c] = x;  // temp: pre-LN value
    float sr = x, qr = x * x;
#pragma unroll
    for (int m = 1; m < 64; m <<= 1) { sr += __shfl_xor(sr, m); qr += __shfl_xor(qr, m); }
    if ((c & 63) == 0) { lnr[c >> 6] = sr; lnr[4 + (c >> 6)] = qr; }
  }
  __syncthreads();
  if (tid < 256) {
    float m = (lnr[0] + lnr[1] + lnr[2] + lnr[3]) * (1.f / 256.f);
    float v = (lnr[4] + lnr[5] + lnr[6] + lnr[7]) * (1.f / 256.f) - m * m;
    float s3 = (s3_s[c] - m) * rsqrtf(v + 1e-5f) * ln_g[c] + ln_b[c];
    s3_s[c] = s3;  // own element only
    if (ph == 0) {
      S[(((long)(b * 16) + t) * 8 + l) * 256 + c] = s3;
      slots_nxt[b * 2048 + l * 256 + c] = s3;
    }
  }
  __syncthreads();
  // Qk ph-half: thread (kc = tid>>7 in [0,8), cc = tid&127), e = kc*32..+32
  {
    int kc = tid >> 7, cc = tid & 127;
    const float* wp = Wqk + (kc * 32) * 256 + ph * 128 + cc;
    const float* sp = s3_s + kc * 32;
    float acc = 0.f;
#pragma unroll
    for (int g = 0; g < 2; ++g) {
      float w[16];
#pragma unroll
      for (int i = 0; i < 16; ++i) w[i] = wp[(g * 16 + i) * 256];
#pragma unroll
      for (int i = 0; i < 16; ++i) acc += sp[g * 16 + i] * w[i];
    }
    red8[cc * 9 + kc] = acc;
  }
  __syncthreads();
  if (tid < 128) {
    float a = bqk[ph * 128 + tid];
#pragma unroll
    for (int kc = 0; kc < 8; ++kc) a += red8[tid * 9 + kc];
    QkG[b * 2048 + l * 256 + ph * 128 + tid] = a;
  }
}

// Post-pass: Beta[b,t,l,:] *= dens_all[t*16+b][l] for all 16 steps at once.
__global__ __launch_bounds__(1024) void beta_norm_kernel(
    const float* __restrict__ dens_all, float* __restrict__ Beta) {
  int wid = blockIdx.x;
  int b = wid >> 4, t = wid & 15;
  int tid = threadIdx.x;
  long base = (((long)b * 16) + t) * 8192;
#pragma unroll
  for (int i = 0; i < 8; ++i) {
    int idx = i * 1024 + tid;
    int l = idx >> 10;
    Beta[base + idx] *= dens_all[(t * 16 + b) * 8 + l];
  }
}

extern "C" void kernel_launch(void* const* d_in, const int* in_sizes, int n_in,
                              void* d_out, int out_size, void* d_ws, size_t ws_size,
                              hipStream_t stream) {
  const float* H    = (const float*)d_in[0];
  const float* eps  = (const float*)d_in[1];
  const float* mu   = (const float*)d_in[2];
  const float* lsig = (const float*)d_in[3];
  const float* Wq   = (const float*)d_in[4];
  const float* bq   = (const float*)d_in[5];
  const float* Wk   = (const float*)d_in[6];
  // d_in[7] = bk: constant per softmax row -> drops out
  const float* Wv   = (const float*)d_in[8];
  const float* bv   = (const float*)d_in[9];
  const float* Wih  = (const float*)d_in[10];
  const float* bih  = (const float*)d_in[11];
  const float* Whh  = (const float*)d_in[12];
  const float* bhh  = (const float*)d_in[13];
  const float* W1   = (const float*)d_in[14];
  const float* b1   = (const float*)d_in[15];
  const float* W2   = (const float*)d_in[16];
  const float* b2   = (const float*)d_in[17];
  const float* ln_g = (const float*)d_in[18];
  const float* ln_b = (const float*)d_in[19];

  float* out = (float*)d_out;
  float* S    = out;                            // [B,K,L,D]
  float* Beta = out + (long)Bn * KK * Ln * Dn;  // [B,K,L,N]

  float* ws = (float*)d_ws;
  float* Wqk    = ws + OFF_WQK;
  float* bqk    = ws + OFF_BQK;
  float* WgiT   = ws + OFF_WGIT;
  float* bgi    = ws + OFF_BGI;
  float* WhhT   = ws + OFF_WHHT;
  float* W1T    = ws + OFF_W1T;
  float* W2T    = ws + OFF_W2T;
  float* slots0 = ws + OFF_SLOTS;   // ping-pong pair
  float* Qk     = ws + OFF_QK;
  float* pav    = ws + OFF_PAV;
  float* pden   = ws + OFF_PDEN;
  float* pg     = ws + OFF_PG;
  float* dens   = ws + OFF_DENS;

  prologue_kernel<<<961, 256, 0, stream>>>(Wq, bq, Wk, Wih, bih, Wv, bv, Whh, W1, W2,
                                           eps, mu, lsig,
                                           Wqk, bqk, WgiT, bgi, WhhT, W1T, W2T, slots0);
  qk0_kernel<<<128, 256, 0, stream>>>(Wqk, bqk, slots0, Qk);

  for (int t = 0; t < KK; ++t) {
    float* scur = slots0 + (t & 1) * 32768;
    float* snxt = slots0 + ((t + 1) & 1) * 32768;
    attn_kernel<<<dim3(32, 16), 256, 0, stream>>>(H, Qk, Beta, pav, pden, t);
    gru_kernel<<<256, 1024, 0, stream>>>(WgiT, WhhT, pav, pden, scur, pg, dens, t);
    chainm_kernel<<<256, 1024, 0, stream>>>(pg, bgi, bhh, W1T, b1, W2T, b2,
                                            Wqk, bqk, ln_g, ln_b, scur, snxt,
                                            S, Qk, t);
  }
  beta_norm_kernel<<<256, 1024, 0, stream>>>(dens, Beta);
}

// Round 6
// 880.649 us; speedup vs baseline: 3.4507x; 1.0088x over previous
//
#include <hip/hip_runtime.h>
#include <math.h>

// RecurrentSlotEncoder: B=16,K=16,N=1024,D=256,L=8
// Algebra: scores = (slots@Wqk) @ h^T      (no K-projection of h)
//          gi     = (attn@h)·rden @ WgiT + bgi, Wgi = W_ih@Wv  (no V-projection)
// R8 structure: 3 launches/step:
//   attn (512 wgs, reg-tiled phase A)
//   gru  (512 wgs = (b,kc16,role): role0 = gi partials (WgiT, upd), role1 = gh
//         partials (WhhT, slots). One 48KB weight stage per wg instead of two
//         sequential -> half the serial chain, 2 wgs/CU for latency overlap.)
//   chainm (256 wgs = (b,l,ph)): pg-combine -> GRU nonlin -> full f1 -> full x
//          -> LN -> s3 -> Qk-half. W1T group-0 prefetched into registers at
//          entry (latency hides under combine+nonlin).
// Prologue merged (961 wgs) + qk0. Beta normalization post-loop.

#define Bn 16
#define KK 16
#define Nn 1024
#define Dn 256
#define Ln 8

// workspace float offsets
#define OFF_WQK   0          // 256*256   Wqk[d][e]
#define OFF_BQK   65536      // 256
#define OFF_WGIT  65792      // 256*768   WgiT[e][jj] = sum_c Wih[jj][c]*Wv[c][e]
#define OFF_BGI   262400     // 768
#define OFF_WHHT  263168     // 256*768   WhhT[e][jj] = Whh[jj][e]
#define OFF_W1T   459776     // 256*256
#define OFF_W2T   525312     // 256*256
#define OFF_SLOTS 590848     // 2 x 128*256 ping-pong
#define OFF_QK    656384     // 128*256
#define OFF_PAV   689152     // [b][tile32][l][256] = 1048576
#define OFF_PDEN  1737728    // [b][tile32][l] = 4096
#define OFF_PG    1741824    // [(b*16+kc)*8+l][1536] = 3145728
#define OFF_DENS  4887552    // [t*16+b][8] = 2048

__device__ __forceinline__ float sigmoidf_(float x) { return 1.f / (1.f + __expf(-x)); }

// Merged prologue: wg 0..256 = p1 (Wqk/bqk), 257..512 = p2 (WgiT/bgi),
// 513..832 = p3 transposes, 833..960 = init_slots.
__global__ __launch_bounds__(256) void prologue_kernel(
    const float* __restrict__ Wq, const float* __restrict__ bq,
    const float* __restrict__ Wk,
    const float* __restrict__ Wih, const float* __restrict__ bih,
    const float* __restrict__ Wv, const float* __restrict__ bv,
    const float* __restrict__ Whh, const float* __restrict__ W1,
    const float* __restrict__ W2,
    const float* __restrict__ eps, const float* __restrict__ mu,
    const float* __restrict__ lsig,
    float* __restrict__ Wqk, float* __restrict__ bqk,
    float* __restrict__ WgiT, float* __restrict__ bgi,
    float* __restrict__ WhhT, float* __restrict__ W1T, float* __restrict__ W2T,
    float* __restrict__ slots) {
  __shared__ float tile[32][33];
  int wg = blockIdx.x, tid = threadIdx.x;
  if (wg < 257) {
    int w = wg;
    if (w < 256) {
      float acc = 0.f;
#pragma unroll 8
      for (int a = 0; a < 256; ++a) acc += Wq[a * 256 + w] * Wk[a * 256 + tid];
      Wqk[w * 256 + tid] = acc;
    } else {
      float acc = 0.f;
#pragma unroll 8
      for (int a = 0; a < 256; ++a) acc += bq[a] * Wk[a * 256 + tid];
      bqk[tid] = acc;
    }
  } else if (wg < 513) {
    int d = wg - 257;
    float a0 = 0.f, a1 = 0.f, a2 = 0.f;
#pragma unroll 4
    for (int c = 0; c < 256; ++c) {
      float wv = Wv[c * 256 + d];  // wave-uniform
      a0 += Wih[tid * 256 + c] * wv;
      a1 += Wih[(tid + 256) * 256 + c] * wv;
      a2 += Wih[(tid + 512) * 256 + c] * wv;
    }
    WgiT[d * 768 + tid] = a0;
    WgiT[d * 768 + 256 + tid] = a1;
    WgiT[d * 768 + 512 + tid] = a2;
    if (d < 3) {
      int jj = d * 256 + tid;
      float s = bih[jj];
      for (int c = 0; c < 256; ++c) s += Wih[jj * 256 + c] * bv[c];
      bgi[jj] = s;
    }
  } else if (wg < 833) {
    int sub = wg - 513;
    const float* in; float* out; int R, C, tr, tc;
    if (sub < 192)      { in = Whh; out = WhhT; R = 768; C = 256; tr = sub >> 3; tc = sub & 7; }
    else if (sub < 256) { in = W1;  out = W1T;  R = 256; C = 256; sub -= 192; tr = sub >> 3; tc = sub & 7; }
    else                { in = W2;  out = W2T;  R = 256; C = 256; sub -= 256; tr = sub >> 3; tc = sub & 7; }
    int r = tid >> 5, c = tid & 31;
#pragma unroll
    for (int k = 0; k < 4; ++k)
      tile[r + 8 * k][c] = in[(tr * 32 + r + 8 * k) * C + tc * 32 + c];
    __syncthreads();
#pragma unroll
    for (int k = 0; k < 4; ++k)
      out[(tc * 32 + r + 8 * k) * R + tr * 32 + c] = tile[c][r + 8 * k];
  } else {
    int idx = (wg - 833) * 256 + tid;  // 0..32767
    int r = idx & 2047;
    slots[idx] = mu[r] + expf(lsig[r]) * eps[idx];
  }
}

// Qk = slots @ Wqk + bqk (t=0 only)
__global__ __launch_bounds__(256) void qk0_kernel(
    const float* __restrict__ Wqk, const float* __restrict__ bqk,
    const float* __restrict__ slots, float* __restrict__ Qkout) {
  __shared__ float sl_s[2048];
  int j = blockIdx.x & 7, b = blockIdx.x >> 3, tid = threadIdx.x;
  for (int k = 0; k < 8; ++k) sl_s[tid + k * 256] = slots[b * 2048 + tid + k * 256];
  __syncthreads();
  int l = tid >> 5, ee = j * 32 + (tid & 31);
  float acc = bqk[ee];
#pragma unroll 8
  for (int d = 0; d < 256; ++d) acc += sl_s[l * 256 + d] * Wqk[d * 256 + ee];
  Qkout[b * 2048 + l * 256 + ee] = acc;
}

// Fused attention: wg = (tile32, b), grid (32,16). Stages 32 rows of H in LDS.
// Phase A reg-tiled: thread (eg8, lh2, rq16) = 2 rows x 4 l x 32-e chunk via
// float4 LDS reads; eg-partials reduced in LDS.
// Phase B: es2[row][8] -> 2 broadcast b128 per row.
__global__ __launch_bounds__(256) void attn_kernel(
    const float* __restrict__ H, const float* __restrict__ Qk,
    float* __restrict__ beta_out, float* __restrict__ par_av,
    float* __restrict__ par_den, int t) {
  __shared__ float h_s[32 * 260];   // stride 260 floats (1040B, 16B-aligned)
  __shared__ float qk_s[8 * 260];
  __shared__ float red_a[8 * 256];  // [eg][l*32+row]
  __shared__ float es2[32 * 8];     // [row][l]
  __shared__ float red[256];        // [l*32+row] for den
  int tile = blockIdx.x, b = blockIdx.y, tid = threadIdx.x;
#pragma unroll
  for (int k = 0; k < 8; ++k) {
    int idx = tid + k * 256, l = idx >> 8, e = idx & 255;
    qk_s[l * 260 + e] = Qk[b * 2048 + idx];
  }
  const float4* src = (const float4*)(H + (((long)b * KK + t) * Nn + tile * 32) * Dn);
#pragma unroll
  for (int k = 0; k < 8; ++k) {
    int idx4 = tid + k * 256, r = idx4 >> 6, d4 = idx4 & 63;
    *(float4*)(&h_s[r * 260 + d4 * 4]) = src[idx4];
  }
  __syncthreads();
  // phase A
  {
    int eg = tid >> 5, lh = (tid >> 4) & 1, rq = tid & 15;
    float4 hA[8], hB[8];
    const float4* ha = (const float4*)(&h_s[(rq * 2) * 260 + eg * 32]);
    const float4* hb = (const float4*)(&h_s[(rq * 2 + 1) * 260 + eg * 32]);
#pragma unroll
    for (int i = 0; i < 8; ++i) { hA[i] = ha[i]; hB[i] = hb[i]; }
    float acc[4][2] = {{0.f, 0.f}, {0.f, 0.f}, {0.f, 0.f}, {0.f, 0.f}};
#pragma unroll
    for (int li = 0; li < 4; ++li) {
      const float4* qv = (const float4*)(&qk_s[(lh * 4 + li) * 260 + eg * 32]);
#pragma unroll
      for (int i = 0; i < 8; ++i) {
        float4 qq = qv[i];
        acc[li][0] += qq.x * hA[i].x + qq.y * hA[i].y + qq.z * hA[i].z + qq.w * hA[i].w;
        acc[li][1] += qq.x * hB[i].x + qq.y * hB[i].y + qq.z * hB[i].z + qq.w * hB[i].w;
      }
    }
#pragma unroll
    for (int li = 0; li < 4; ++li) {
      red_a[eg * 256 + (lh * 4 + li) * 32 + rq * 2] = acc[li][0];
      red_a[eg * 256 + (lh * 4 + li) * 32 + rq * 2 + 1] = acc[li][1];
    }
  }
  __syncthreads();
  // reduce eg-partials -> exp -> Beta + den staging
  {
    int l = tid >> 5, row = tid & 31;
    float a = 0.f;
#pragma unroll
    for (int eg = 0; eg < 8; ++eg) a += red_a[eg * 256 + l * 32 + row];
    float ev = __expf(a * 0.0625f);  // 1/sqrt(256); no max-sub (|s| small)
    es2[row * 8 + l] = ev;
    red[tid] = ev;
    beta_out[(((long)b * KK + t) * Ln + l) * Nn + tile * 32 + row] = ev;
  }
  __syncthreads();
  if (tid < 8) {
    float s = 0.f;
    for (int i = 0; i < 32; ++i) s += red[tid * 32 + i];
    par_den[(b * 32 + tile) * 8 + tid] = s;
  }
  // phase B: av[l] += e[row][l] * h[row][d=tid]
  float av[8] = {0.f, 0.f, 0.f, 0.f, 0.f, 0.f, 0.f, 0.f};
  for (int rr = 0; rr < 32; ++rr) {
    float hv = h_s[rr * 260 + tid];
    float4 ea = *(const float4*)(&es2[rr * 8]);
    float4 eb = *(const float4*)(&es2[rr * 8 + 4]);
    av[0] += ea.x * hv; av[1] += ea.y * hv; av[2] += ea.z * hv; av[3] += ea.w * hv;
    av[4] += eb.x * hv; av[5] += eb.y * hv; av[6] += eb.z * hv; av[7] += eb.w * hv;
  }
  long pbase = (long)(b * 32 + tile) * 2048;
#pragma unroll
  for (int i = 0; i < 8; ++i) par_av[pbase + i * 256 + tid] = av[i];
}

// GRU partial kernel, role-split: wg = (b, kc16, role), 512 wgs x 1024 thr,
// 2 wgs/CU. role0: stage WgiT slice, reduce par_av -> upd (scaled 1/den),
// gi partials (cols 0..767). role1: stage WhhT slice, slots slice, gh partials
// (cols 768..1535). pg rows shared, column ranges disjoint.
__global__ __launch_bounds__(1024) void gru_kernel(
    const float* __restrict__ WgiT, const float* __restrict__ WhhT,
    const float* __restrict__ par_av, const float* __restrict__ par_den,
    const float* __restrict__ slots_cur, float* __restrict__ pg,
    float* __restrict__ dens_all, int t) {
  __shared__ float w_s[16 * 768];  // 48KB staged slice
  __shared__ float rupd[8][128];
  __shared__ float x_s[128];       // upd (role0) or slots slice (role1)
  __shared__ float den_s[8];
  int wid = blockIdx.x;
  int b = wid & 15, kc = (wid >> 4) & 15, role = wid >> 8;
  int tid = threadIdx.x;

  const float* W = role ? (WhhT + kc * 12288) : (WgiT + kc * 12288);
  const float4* wsrc = (const float4*)W;
  float4 wv0 = wsrc[tid], wv1 = wsrc[tid + 1024], wv2 = wsrc[tid + 2048];
  if (role == 0) {
    {
      int g = tid >> 7, le = tid & 127;  // le = l*16+e
      int l = le >> 4, e = le & 15;
      float ps = 0.f;
      long base = ((long)(b * 32)) * 2048 + l * 256 + kc * 16 + e;
#pragma unroll
      for (int i = 0; i < 4; ++i) ps += par_av[base + (long)(g * 4 + i) * 2048];
      rupd[g][le] = ps;
    }
    if (tid < 256) {
      int ll = tid >> 5, tl = tid & 31;
      float dv = par_den[(b * 32 + tl) * 8 + ll];
#pragma unroll
      for (int m = 1; m < 32; m <<= 1) dv += __shfl_xor(dv, m);
      if (tl == 0) den_s[ll] = 1.f / dv;
    }
  } else {
    if (tid < 128) x_s[tid] = slots_cur[b * 2048 + (tid >> 4) * 256 + kc * 16 + (tid & 15)];
  }
  ((float4*)w_s)[tid] = wv0;
  ((float4*)w_s)[tid + 1024] = wv1;
  ((float4*)w_s)[tid + 2048] = wv2;
  __syncthreads();

  if (role == 0) {
    if (kc == 0 && tid < 8) dens_all[(t * 16 + b) * 8 + tid] = den_s[tid];
    if (tid < 128) {
      float s = 0.f;
#pragma unroll
      for (int g = 0; g < 8; ++g) s += rupd[g][tid];
      x_s[tid] = s * den_s[tid >> 4];
    }
    __syncthreads();
  }

  // partials: thread = (l4 = tid>>8, cb = tid&255) covers rows {l4, l4+4}
  // and cols {cb, cb+256, cb+512} of its role's column block.
  int l4 = tid >> 8, cb = tid & 255;
  int off = role ? 768 : 0;
  long pb0 = ((long)(b * 16 + kc) * 8 + l4) * 1536 + off;
  long pb1 = ((long)(b * 16 + kc) * 8 + l4 + 4) * 1536 + off;
  {
    float a0 = 0.f, a1 = 0.f, a2 = 0.f, a3 = 0.f, a4 = 0.f, a5 = 0.f;
#pragma unroll
    for (int e = 0; e < 16; ++e) {
      float u0 = x_s[l4 * 16 + e];
      float u1 = x_s[(l4 + 4) * 16 + e];
      float w0 = w_s[e * 768 + cb];
      float w1 = w_s[e * 768 + 256 + cb];
      float w2 = w_s[e * 768 + 512 + cb];
      a0 += u0 * w0; a1 += u0 * w1; a2 += u0 * w2;
      a3 += u1 * w0; a4 += u1 * w1; a5 += u1 * w2;
    }
    pg[pb0 + cb] = a0; pg[pb0 + 256 + cb] = a1; pg[pb0 + 512 + cb] = a2;
    pg[pb1 + cb] = a3; pg[pb1 + 256 + cb] = a4; pg[pb1 + 512 + cb] = a5;
  }
}

// chainm: wg = (b, l, ph), 256 wgs x 1024 thr. pg-combine -> GRU nonlin ->
// full f1 -> full x -> LN -> s3 (ph0 writes S/slots_nxt) -> Qk ph-half.
// W1T group-0 prefetched into regs at entry (hides under combine+nonlin).
__global__ __launch_bounds__(1024) void chainm_kernel(
    const float* __restrict__ pg, const float* __restrict__ bgi,
    const float* __restrict__ bhh,
    const float* __restrict__ W1T, const float* __restrict__ b1,
    const float* __restrict__ W2T, const float* __restrict__ b2,
    const float* __restrict__ Wqk, const float* __restrict__ bqk,
    const float* __restrict__ ln_g, const float* __restrict__ ln_b,
    const float* __restrict__ slots_cur, float* __restrict__ slots_nxt,
    float* __restrict__ S, float* __restrict__ QkG, int t) {
  __shared__ float gsum[1536];
  __shared__ float s2_s[256], f1s[256], s3_s[256];
  __shared__ float red4[1024];
  __shared__ float red8[128 * 9];
  __shared__ float lnr[8];
  int wid = blockIdx.x;
  int b = wid & 15, l = (wid >> 4) & 7, ph = wid >> 7;
  int tid = threadIdx.x, q = tid >> 8, c = tid & 255;

  // early-issue W1T group-0 loads (independent of everything below)
  float w1p[16];
  {
    const float* wp = W1T + (q * 64) * 256 + c;
#pragma unroll
    for (int i = 0; i < 16; ++i) w1p[i] = wp[i * 256];
  }

  // combine GRU partials over 16 kc slices (16 loads in flight)
  for (int col = tid; col < 1536; col += 1024) {
    float v[16];
#pragma unroll
    for (int j = 0; j < 16; ++j) v[j] = pg[((long)(b * 16 + j) * 8 + l) * 1536 + col];
    float a = 0.f;
#pragma unroll
    for (int j = 0; j < 16; ++j) a += v[j];
    gsum[col] = a;
  }
  __syncthreads();
  if (tid < 256) {
    float r = sigmoidf_(gsum[c] + bgi[c] + gsum[768 + c] + bhh[c]);
    float z = sigmoidf_(gsum[256 + c] + bgi[256 + c] + gsum[1024 + c] + bhh[256 + c]);
    float n = tanhf(gsum[512 + c] + bgi[512 + c] + r * (gsum[1280 + c] + bhh[512 + c]));
    s2_s[c] = (1.f - z) * n + z * slots_cur[b * 2048 + l * 256 + c];
  }
  __syncthreads();
  // f1 full: thread (q,c), e = q*64..+64; group 0 from prefetch regs
  {
    const float* wp = W1T + (q * 64) * 256 + c;
    const float* sp = s2_s + q * 64;
    float acc = 0.f;
#pragma unroll
    for (int i = 0; i < 16; ++i) acc += sp[i] * w1p[i];
#pragma unroll
    for (int g = 1; g < 4; ++g) {
      float w[16];
#pragma unroll
      for (int i = 0; i < 16; ++i) w[i] = wp[(g * 16 + i) * 256];
#pragma unroll
      for (int i = 0; i < 16; ++i) acc += sp[g * 16 + i] * w[i];
    }
    red4[q * 256 + c] = acc;
  }
  __syncthreads();
  if (tid < 256)
    f1s[c] = fmaxf(red4[c] + red4[256 + c] + red4[512 + c] + red4[768 + c] + b1[c], 0.f);
  __syncthreads();
  // x full: thread (q,c), e = q*64..+64
  {
    const float* wp = W2T + (q * 64) * 256 + c;
    const float* fp = f1s + q * 64;
    float acc = 0.f;
#pragma unroll
    for (int g = 0; g < 4; ++g) {
      float w[16];
#pragma unroll
      for (int i = 0; i < 16; ++i) w[i] = wp[(g * 16 + i) * 256];
#pragma unroll
      for (int i = 0; i < 16; ++i) acc += fp[g * 16 + i] * w[i];
    }
    red4[q * 256 + c] = acc;
  }
  __syncthreads();
  if (tid < 256) {
    float x = red4[c] + red4[256 + c] + red4[512 + c] + red4[768 + c] + b2[c] + s2_s[c];
    s3_s[c] = x;  // temp: pre-LN value
    float sr = x, qr = x * x;
#pragma unroll
    for (int m = 1; m < 64; m <<= 1) { sr += __shfl_xor(sr, m); qr += __shfl_xor(qr, m); }
    if ((c & 63) == 0) { lnr[c >> 6] = sr; lnr[4 + (c >> 6)] = qr; }
  }
  __syncthreads();
  if (tid < 256) {
    float m = (lnr[0] + lnr[1] + lnr[2] + lnr[3]) * (1.f / 256.f);
    float v = (lnr[4] + lnr[5] + lnr[6] + lnr[7]) * (1.f / 256.f) - m * m;
    float s3 = (s3_s[c] - m) * rsqrtf(v + 1e-5f) * ln_g[c] + ln_b[c];
    s3_s[c] = s3;  // own element only
    if (ph == 0) {
      S[(((long)(b * 16) + t) * 8 + l) * 256 + c] = s3;
      slots_nxt[b * 2048 + l * 256 + c] = s3;
    }
  }
  __syncthreads();
  // Qk ph-half: thread (kc = tid>>7 in [0,8), cc = tid&127), e = kc*32..+32
  {
    int kc = tid >> 7, cc = tid & 127;
    const float* wp = Wqk + (kc * 32) * 256 + ph * 128 + cc;
    const float* sp = s3_s + kc * 32;
    float acc = 0.f;
#pragma unroll
    for (int g = 0; g < 2; ++g) {
      float w[16];
#pragma unroll
      for (int i = 0; i < 16; ++i) w[i] = wp[(g * 16 + i) * 256];
#pragma unroll
      for (int i = 0; i < 16; ++i) acc += sp[g * 16 + i] * w[i];
    }
    red8[cc * 9 + kc] = acc;
  }
  __syncthreads();
  if (tid < 128) {
    float a = bqk[ph * 128 + tid];
#pragma unroll
    for (int kc = 0; kc < 8; ++kc) a += red8[tid * 9 + kc];
    QkG[b * 2048 + l * 256 + ph * 128 + tid] = a;
  }
}

// Post-pass: Beta[b,t,l,:] *= dens_all[t*16+b][l] for all 16 steps at once.
__global__ __launch_bounds__(1024) void beta_norm_kernel(
    const float* __restrict__ dens_all, float* __restrict__ Beta) {
  int wid = blockIdx.x;
  int b = wid >> 4, t = wid & 15;
  int tid = threadIdx.x;
  long base = (((long)b * 16) + t) * 8192;
#pragma unroll
  for (int i = 0; i < 8; ++i) {
    int idx = i * 1024 + tid;
    int l = idx >> 10;
    Beta[base + idx] *= dens_all[(t * 16 + b) * 8 + l];
  }
}

extern "C" void kernel_launch(void* const* d_in, const int* in_sizes, int n_in,
                              void* d_out, int out_size, void* d_ws, size_t ws_size,
                              hipStream_t stream) {
  const float* H    = (const float*)d_in[0];
  const float* eps  = (const float*)d_in[1];
  const float* mu   = (const float*)d_in[2];
  const float* lsig = (const float*)d_in[3];
  const float* Wq   = (const float*)d_in[4];
  const float* bq   = (const float*)d_in[5];
  const float* Wk   = (const float*)d_in[6];
  // d_in[7] = bk: constant per softmax row -> drops out
  const float* Wv   = (const float*)d_in[8];
  const float* bv   = (const float*)d_in[9];
  const float* Wih  = (const float*)d_in[10];
  const float* bih  = (const float*)d_in[11];
  const float* Whh  = (const float*)d_in[12];
  const float* bhh  = (const float*)d_in[13];
  const float* W1   = (const float*)d_in[14];
  const float* b1   = (const float*)d_in[15];
  const float* W2   = (const float*)d_in[16];
  const float* b2   = (const float*)d_in[17];
  const float* ln_g = (const float*)d_in[18];
  const float* ln_b = (const float*)d_in[19];

  float* out = (float*)d_out;
  float* S    = out;                            // [B,K,L,D]
  float* Beta = out + (long)Bn * KK * Ln * Dn;  // [B,K,L,N]

  float* ws = (float*)d_ws;
  float* Wqk    = ws + OFF_WQK;
  float* bqk    = ws + OFF_BQK;
  float* WgiT   = ws + OFF_WGIT;
  float* bgi    = ws + OFF_BGI;
  float* WhhT   = ws + OFF_WHHT;
  float* W1T    = ws + OFF_W1T;
  float* W2T    = ws + OFF_W2T;
  float* slots0 = ws + OFF_SLOTS;   // ping-pong pair
  float* Qk     = ws + OFF_QK;
  float* pav    = ws + OFF_PAV;
  float* pden   = ws + OFF_PDEN;
  float* pg     = ws + OFF_PG;
  float* dens   = ws + OFF_DENS;

  prologue_kernel<<<961, 256, 0, stream>>>(Wq, bq, Wk, Wih, bih, Wv, bv, Whh, W1, W2,
                                           eps, mu, lsig,
                                           Wqk, bqk, WgiT, bgi, WhhT, W1T, W2T, slots0);
  qk0_kernel<<<128, 256, 0, stream>>>(Wqk, bqk, slots0, Qk);

  for (int t = 0; t < KK; ++t) {
    float* scur = slots0 + (t & 1) * 32768;
    float* snxt = slots0 + ((t + 1) & 1) * 32768;
    attn_kernel<<<dim3(32, 16), 256, 0, stream>>>(H, Qk, Beta, pav, pden, t);
    gru_kernel<<<512, 1024, 0, stream>>>(WgiT, WhhT, pav, pden, scur, pg, dens, t);
    chainm_kernel<<<256, 1024, 0, stream>>>(pg, bgi, bhh, W1T, b1, W2T, b2,
                                            Wqk, bqk, ln_g, ln_b, scur, snxt,
                                            S, Qk, t);
  }
  beta_norm_kernel<<<256, 1024, 0, stream>>>(dens, Beta);
}